// Round 6
// baseline (701.004 us; speedup 1.0000x reference)
//
#include <hip/hip_runtime.h>
#include <math.h>

#define N_TOK 65536
#define D_DIM 256
#define C_NUM 1024

// d_out layout (floats): out (D*N) | indices (N) | loss (1) | distances (N*C)
#define OUT_OFF   0
#define IDX_OFF   (D_DIM * N_TOK)            // 16777216
#define LOSS_OFF  (IDX_OFF + N_TOK)          // 16842752
#define DIST_OFF  (LOSS_OFF + 1)             // 16842753

#define MARGIN 0.01f
#define NPART 4096

typedef __attribute__((ext_vector_type(8))) short bf16x8;
typedef __attribute__((ext_vector_type(4))) float f32x4;

static __device__ __forceinline__ unsigned short f2bf(float f) {
  unsigned int u = __float_as_uint(f);
  unsigned int r = (u + 0x7fffu + ((u >> 16) & 1u)) >> 16;
  return (unsigned short)r;
}
static __device__ __forceinline__ float bf2f(unsigned short h) {
  return __uint_as_float(((unsigned int)h) << 16);
}

// ===========================================================================
// PATH A (ws_size >= WS_NEEDED):
//   out region (64MB, dead until k4) holds Xh (32MB) | Xl (32MB), [n][k] bf16.
//   x2 lives in IDX region (overwritten by k3a2's indices later).
//   ws: Eh | El | e2 | loss partials | per-(token,group) argmax records.
// k2c round-6: ROLLED unroll-2 K-loop (round-5's full unroll + prefetch
// regressed 225->315us: straight-line code >> I-cache, both pipes idled).
// LDS halved: only Xh staged (33.8KB -> 4 blocks/CU, 16 waves/CU, double
// latency hiding); Xl fragments read from global L2 (pattern numerically
// validated in round-3's all-global k2b). MFMA order unchanged -> bitwise-
// identical distances. Records epilogue + k3a2 fast-path validated round 5.
// ===========================================================================

// ws byte offsets
#define WS_EH   0                            // u16[1024*256]   512KB
#define WS_EL   524288                       // u16[1024*256]   512KB
#define WS_E2   1048576                      // f32[1024]       4KB
#define WS_PART 1052672                      // f32[4096]       16KB
#define WS_TP   1069056                      // uint2[65536*16] 8MB
#define WS_NEEDED (WS_TP + (size_t)N_TOK * 16 * 8)

// Xh/Xl float offsets inside out region
#define XH_OFF_F 0
#define XL_OFF_F 8388608

// loss partials float offset (path B only; inside dead region)
#define PART_OFF_F 263168

// ---------------------------------------------------------------------------
// kA2: bid<1024: transpose+convert X -> Xh/Xl [n][k] (64 tokens per block).
//      1024..1039: convert E -> Eh/El + e2 (in ws).
//      1040..1295: x2[n] -> IDX region (verbatim old order -> bitwise same).
// ---------------------------------------------------------------------------
__global__ __launch_bounds__(256) void kA2_prep(const float* __restrict__ X,
                                                const float* __restrict__ E,
                                                float* __restrict__ out,
                                                unsigned char* __restrict__ ws) {
  const int bid = blockIdx.x, tid = threadIdx.x;
  if (bid < 1024) {
    // X transpose+convert: thread owns token n, d-segment sg (16 d's/chunk)
    unsigned short* XhG = (unsigned short*)(out + XH_OFF_F);
    unsigned short* XlG = (unsigned short*)(out + XL_OFF_F);
    const int n = bid * 64 + (tid >> 2);
    const int sg = (tid & 3) * 16;
    unsigned short* xh = XhG + (size_t)n * D_DIM;
    unsigned short* xl = XlG + (size_t)n * D_DIM;
#pragma unroll 1
    for (int dc = 0; dc < D_DIM; dc += 64) {
      float v[16];
#pragma unroll
      for (int j = 0; j < 16; ++j) v[j] = X[(size_t)(dc + sg + j) * N_TOK + n];
      unsigned short hh[16], ll[16];
#pragma unroll
      for (int j = 0; j < 16; ++j) {
        hh[j] = f2bf(v[j]);
        ll[j] = f2bf(v[j] - bf2f(hh[j]));
      }
      *(bf16x8*)(xh + dc + sg) = *(bf16x8*)&hh[0];
      *(bf16x8*)(xh + dc + sg + 8) = *(bf16x8*)&hh[8];
      *(bf16x8*)(xl + dc + sg) = *(bf16x8*)&ll[0];
      *(bf16x8*)(xl + dc + sg + 8) = *(bf16x8*)&ll[8];
    }
  } else if (bid < 1040) {
    unsigned short* EhG = (unsigned short*)(ws + WS_EH);
    unsigned short* ElG = (unsigned short*)(ws + WS_EL);
    float* e2p = (float*)(ws + WS_E2);
    const int lane = tid & 63, w = tid >> 6;
#pragma unroll 1
    for (int cc = 0; cc < 16; ++cc) {
      const int c = (bid - 1024) * 64 + w * 16 + cc;
      const float4 v = *(const float4*)(E + (size_t)c * D_DIM + lane * 4);
      unsigned short h0 = f2bf(v.x), h1 = f2bf(v.y), h2 = f2bf(v.z), h3 = f2bf(v.w);
      unsigned short l0 = f2bf(v.x - bf2f(h0)), l1 = f2bf(v.y - bf2f(h1));
      unsigned short l2 = f2bf(v.z - bf2f(h2)), l3 = f2bf(v.w - bf2f(h3));
      ushort4 hv = make_ushort4(h0, h1, h2, h3);
      ushort4 lv = make_ushort4(l0, l1, l2, l3);
      *(ushort4*)(EhG + (size_t)c * D_DIM + lane * 4) = hv;
      *(ushort4*)(ElG + (size_t)c * D_DIM + lane * 4) = lv;
      float s = v.x * v.x + v.y * v.y + v.z * v.z + v.w * v.w;
#pragma unroll
      for (int off = 32; off; off >>= 1) s += __shfl_down(s, off, 64);
      if (lane == 0) e2p[c] = s;
    }
  } else {
    const int n = (bid - 1040) * 256 + tid;
    float s = 0.0f;
#pragma unroll 8
    for (int d = 0; d < D_DIM; ++d) {
      float v = X[(size_t)d * N_TOK + n];
      s = fmaf(v, v, s);
    }
    out[IDX_OFF + n] = s;                    // x2 scratch (k3a2 overwrites later)
  }
}

// ---------------------------------------------------------------------------
// k2c: Xh-only LDS stage (33.8KB -> 4 blocks/CU), rolled unroll-2 loop,
// Xl + B fragments from global (L2-hot). Records epilogue.
// Block = 64 tokens x 256 codes, 4 waves; wave w owns 64 codes.
// ---------------------------------------------------------------------------
#define TM 64
#define TC 256
#define BK 32
#define XS2 264   // u16 row stride (256 + 8 pad); 528B, 16B-aligned

__global__ __launch_bounds__(256) void k2c_dist(float* __restrict__ out,
                                                unsigned char* __restrict__ ws) {
  __shared__ __align__(16) unsigned short xh[TM * XS2];   // 33.8KB only

  const unsigned short* __restrict__ XhG = (const unsigned short*)(out + XH_OFF_F);
  const unsigned short* __restrict__ XlG = (const unsigned short*)(out + XL_OFF_F);
  const unsigned short* __restrict__ EhG = (const unsigned short*)(ws + WS_EH);
  const float* __restrict__ e2p = (const float*)(ws + WS_E2);
  uint2* __restrict__ tp = (uint2*)(ws + WS_TP);

  const int tid = threadIdx.x;
  const int lane = tid & 63, wave = tid >> 6;

  // XCD-swizzled decode (4 code-tiles of a token-tile land on the same XCD)
  const int bid = blockIdx.x;
  const int xcd = bid & 7;
  const int slot = bid >> 3;
  const int bx = slot & 3;
  const int by = xcd * 128 + (slot >> 2);
  const int c0 = bx * TC;
  const int n0 = by * TM;

  const int wc = c0 + wave * 64;
  const int m = lane & 15;
  const int q = lane >> 4;

  // ---- stage Xh tile once: thread owns token tl, 64-u16 segment ----
  {
    const int tl = tid >> 2;
    const int seg = (tid & 3) * 64;
    const unsigned short* gh = XhG + (size_t)(n0 + tl) * D_DIM + seg;
    unsigned short* sh = xh + tl * XS2 + seg;
#pragma unroll
    for (int j = 0; j < 8; ++j)
      *(bf16x8*)(sh + j * 8) = *(const bf16x8*)(gh + j * 8);
  }
  __syncthreads();   // the only barrier in this kernel

  f32x4 acc[4][4];
#pragma unroll
  for (int i = 0; i < 4; ++i)
#pragma unroll
    for (int t = 0; t < 4; ++t) acc[i][t] = (f32x4){0.f, 0.f, 0.f, 0.f};

  // hoisted fragment base pointers (row*256 + q*8), offset by kb in loop
  const unsigned short* bp[4];
#pragma unroll
  for (int t = 0; t < 4; ++t) bp[t] = EhG + (size_t)(wc + t * 16 + m) * D_DIM + q * 8;
  const unsigned short* alp[4];
#pragma unroll
  for (int i = 0; i < 4; ++i) alp[i] = XlG + (size_t)(n0 + i * 16 + m) * D_DIM + q * 8;
  const size_t loEu = (size_t)(WS_EL - WS_EH) / 2;        // u16 delta Eh->El

#pragma unroll 2
  for (int kb = 0; kb < D_DIM; kb += BK) {
    bf16x8 ah[4], al[4], bh[4], bl[4];
#pragma unroll
    for (int t = 0; t < 4; ++t) {
      bh[t] = *(const bf16x8*)(bp[t] + kb);
      bl[t] = *(const bf16x8*)(bp[t] + loEu + kb);
    }
#pragma unroll
    for (int i = 0; i < 4; ++i) {
      const int ro = (i * 16 + m) * XS2 + kb + q * 8;
      ah[i] = *(const bf16x8*)&xh[ro];
      al[i] = *(const bf16x8*)(alp[i] + kb);
    }
#pragma unroll
    for (int i = 0; i < 4; ++i)
#pragma unroll
      for (int t = 0; t < 4; ++t) {
        acc[i][t] = __builtin_amdgcn_mfma_f32_16x16x32_bf16(ah[i], bh[t], acc[i][t], 0, 0, 0);
        acc[i][t] = __builtin_amdgcn_mfma_f32_16x16x32_bf16(ah[i], bl[t], acc[i][t], 0, 0, 0);
        acc[i][t] = __builtin_amdgcn_mfma_f32_16x16x32_bf16(al[i], bh[t], acc[i][t], 0, 0, 0);
      }
  }

  // ---- epilogue: distances + per-(token, 64-code group) argmax records ----
  float e2v[4];
#pragma unroll
  for (int t = 0; t < 4; ++t) e2v[t] = e2p[wc + t * 16 + m];

#pragma unroll
  for (int i = 0; i < 4; ++i) {
#pragma unroll
    for (int r = 0; r < 4; ++r) {
      const int tok = n0 + i * 16 + q * 4 + r;
      const float x2v = out[IDX_OFF + tok];
      const size_t row = DIST_OFF + (size_t)tok * C_NUM;
      float dv[4];
      float bestv = -3.4e38f;
      int bidx = 0;
#pragma unroll
      for (int t = 0; t < 4; ++t) {
        float d2 = fmaf(-2.0f, acc[i][t][r], x2v + e2v[t]);
        d2 = fmaxf(d2, 0.0f);
        const float dd = -sqrtf(d2);
        dv[t] = dd;
        out[row + wc + t * 16 + m] = dd;
        if (dd > bestv) { bestv = dd; bidx = wc + t * 16 + m; }
      }
      // lex (val desc, idx asc) reduce across the 16 m-lanes (same q)
#pragma unroll
      for (int off = 1; off < 16; off <<= 1) {
        const float ov = __shfl_xor(bestv, off, 64);
        const int oi = __shfl_xor(bidx, off, 64);
        if (ov > bestv || (ov == bestv && oi < bidx)) { bestv = ov; bidx = oi; }
      }
      // count of this group's codes within MARGIN of the group best
      const float thr2 = bestv - MARGIN;
      int cnt = 0;
#pragma unroll
      for (int t = 0; t < 4; ++t) cnt += (dv[t] > thr2) ? 1 : 0;
#pragma unroll
      for (int off = 1; off < 16; off <<= 1) cnt += __shfl_xor(cnt, off, 64);
      if ((lane & 15) == 0) {
        tp[(size_t)tok * 16 + bx * 4 + wave] =
            make_uint2(__float_as_uint(bestv),
                       (unsigned)bidx | ((unsigned)cnt << 16));
      }
    }
  }
}

// ---------------------------------------------------------------------------
// k3a2: per token read 16 records (128B). Fast path (exactly one group
// within MARGIN of global best AND that group's cnt == 1): winner = record
// idx, loss = best^2 — exactly the old total==1 condition. Otherwise run the
// round-1 full-row algorithm verbatim on the stored distance row.
// Block = 16 tokens (4 waves x 4 tokens; 16 lanes per token).
// ---------------------------------------------------------------------------
__global__ __launch_bounds__(256) void k3a2_argmax(const float* __restrict__ X,
                                                   const float* __restrict__ E,
                                                   float* __restrict__ out,
                                                   unsigned char* __restrict__ ws) {
  const uint2* __restrict__ tp = (const uint2*)(ws + WS_TP);
  float* __restrict__ part = (float*)(ws + WS_PART);
  __shared__ float lsum[4];
  const int tid = threadIdx.x, lane = tid & 63, w = tid >> 6;
  const int g = lane & 15, seg = lane >> 4;
  const int n = blockIdx.x * 16 + w * 4 + seg;

  const uint2 rec = tp[(size_t)n * 16 + g];
  const float val = __uint_as_float(rec.x);
  const int idx = (int)(rec.y & 0xffffu);
  const int cnt = (int)(rec.y >> 16);

  float best = val;
  int bi = idx, bc = cnt;
#pragma unroll
  for (int off = 1; off < 16; off <<= 1) {
    const float ov = __shfl_xor(best, off, 64);
    const int oi = __shfl_xor(bi, off, 64);
    const int oc = __shfl_xor(bc, off, 64);
    if (ov > best || (ov == best && oi < bi)) { best = ov; bi = oi; bc = oc; }
  }
  const float thr = best - MARGIN;
  const unsigned long long bal = __ballot(val > thr);
  const int m16 = (int)((bal >> (seg * 16)) & 0xffffull);
  const bool fast = (__popc((unsigned)m16) == 1) && (bc == 1);

  float lval = 0.0f;
  if (fast && g == 0) {
    out[IDX_OFF + n] = (float)bi;
    lval = best * best;
  }

  // slow segments: whole wave runs the old full-row algorithm per token
  unsigned long long smask = __ballot((!fast) && (g == 0));
  float sloss = 0.0f;
  while (smask) {
    const int sl = __ffsll((long long)smask) - 1;
    smask &= smask - 1;
    const int nn = blockIdx.x * 16 + w * 4 + (sl >> 4);
    {
      const float* row = out + DIST_OFF + (size_t)nn * C_NUM;
      float v[16];
      float bestf = -3.4e38f;
      int bif = 0x7fffffff;
#pragma unroll
      for (int j = 0; j < 16; ++j) {
        v[j] = row[j * 64 + lane];
        if (v[j] > bestf) { bestf = v[j]; bif = j * 64 + lane; }
      }
#pragma unroll
      for (int off = 32; off; off >>= 1) {
        const float ov = __shfl_xor(bestf, off, 64);
        const int oi = __shfl_xor(bif, off, 64);
        if (ov > bestf || (ov == bestf && oi < bif)) { bestf = ov; bif = oi; }
      }
      const float thrf = bestf - MARGIN;
      unsigned long long masks[16];
      int total = 0;
#pragma unroll
      for (int j = 0; j < 16; ++j) {
        masks[j] = __ballot(v[j] > thrf);
        total += __popcll(masks[j]);
      }
      float best_d2 = bestf * bestf;
      int best_idx = bif;
      if (total > 1) {
        best_d2 = 3.4e38f;
        best_idx = 0x7fffffff;
        for (int j = 0; j < 16; ++j) {
          unsigned long long mm = masks[j];
          while (mm) {
            const int l = __ffsll((long long)mm) - 1;
            mm &= mm - 1;
            const int c = j * 64 + l;
            float sx = 0.f, se = 0.f, sxe = 0.f;
#pragma unroll
            for (int r = 0; r < 4; ++r) {
              const int d = r * 64 + lane;
              const float xv = X[(size_t)d * N_TOK + nn];
              const float ev = E[(size_t)c * D_DIM + d];
              sx = fmaf(xv, xv, sx);
              se = fmaf(ev, ev, se);
              sxe = fmaf(xv, ev, sxe);
            }
            float d2 = fmaf(-2.f, sxe, sx + se);
#pragma unroll
            for (int off = 32; off; off >>= 1) d2 += __shfl_xor(d2, off, 64);
            d2 = fmaxf(d2, 0.f);
            if (d2 < best_d2 || (d2 == best_d2 && c < best_idx)) {
              best_d2 = d2; best_idx = c;
            }
          }
        }
      }
      if (lane == 0) {
        out[IDX_OFF + nn] = (float)best_idx;
        sloss += best_d2;
      }
    }
  }

  float wl = lval + ((lane == 0) ? sloss : 0.0f);
#pragma unroll
  for (int off = 32; off; off >>= 1) wl += __shfl_down(wl, off, 64);
  if (lane == 0) lsum[w] = wl;
  __syncthreads();
  if (tid == 0)
    part[blockIdx.x] = lsum[0] + lsum[1] + lsum[2] + lsum[3];
}

__global__ __launch_bounds__(256) void k3b2_loss(float* __restrict__ out,
                                                 unsigned char* __restrict__ ws) {
  const float* __restrict__ part = (const float*)(ws + WS_PART);
  __shared__ float red[4];
  const int tid = threadIdx.x, lane = tid & 63, w = tid >> 6;
  float s = 0.0f;
#pragma unroll
  for (int i = 0; i < NPART / 256; ++i) s += part[i * 256 + tid];
#pragma unroll
  for (int off = 32; off; off >>= 1) s += __shfl_down(s, off, 64);
  if (lane == 0) red[w] = s;
  __syncthreads();
  if (tid == 0)
    out[LOSS_OFF] = (red[0] + red[1] + red[2] + red[3]) *
                    (0.25f / ((float)N_TOK * (float)D_DIM));
}

// ===========================================================================
// PATH B (fallback, ws unusable): round-1 kernels verbatim.
// ===========================================================================
#define EH_OFF_F  0
#define EL_OFF_F  131072
#define E2_OFF_F  262144

__global__ __launch_bounds__(256) void kA_prep(const float* __restrict__ X,
                                               const float* __restrict__ E,
                                               float* __restrict__ out) {
  const int bid = blockIdx.x, tid = threadIdx.x;
  if (bid < 256) {
    const int n = bid * 256 + tid;
    float s = 0.0f;
#pragma unroll 8
    for (int d = 0; d < D_DIM; ++d) {
      float v = X[(size_t)d * N_TOK + n];
      s = fmaf(v, v, s);
    }
    out[IDX_OFF + n] = s;
  } else {
    unsigned short* EhG = (unsigned short*)(out + EH_OFF_F);
    unsigned short* ElG = (unsigned short*)(out + EL_OFF_F);
    const int lane = tid & 63, w = tid >> 6;
#pragma unroll 1
    for (int cc = 0; cc < 16; ++cc) {
      const int c = (bid - 256) * 64 + w * 16 + cc;
      const float4 v = *(const float4*)(E + (size_t)c * D_DIM + lane * 4);
      unsigned short h0 = f2bf(v.x), h1 = f2bf(v.y), h2 = f2bf(v.z), h3 = f2bf(v.w);
      unsigned short l0 = f2bf(v.x - bf2f(h0)), l1 = f2bf(v.y - bf2f(h1));
      unsigned short l2 = f2bf(v.z - bf2f(h2)), l3 = f2bf(v.w - bf2f(h3));
      ushort4 hv = make_ushort4(h0, h1, h2, h3);
      ushort4 lv = make_ushort4(l0, l1, l2, l3);
      *(ushort4*)(EhG + (size_t)c * D_DIM + lane * 4) = hv;
      *(ushort4*)(ElG + (size_t)c * D_DIM + lane * 4) = lv;
      float s = v.x * v.x + v.y * v.y + v.z * v.z + v.w * v.w;
#pragma unroll
      for (int off = 32; off; off >>= 1) s += __shfl_down(s, off, 64);
      if (lane == 0) out[E2_OFF_F + c] = s;
    }
  }
}

#define XS 40

__global__ __launch_bounds__(256) void k2_dist(const float* __restrict__ X,
                                               float* __restrict__ out) {
  __shared__ __align__(16) unsigned short xhb[2][TM * XS];
  __shared__ __align__(16) unsigned short xlb[2][TM * XS];

  const unsigned short* __restrict__ EhG = (const unsigned short*)(out + EH_OFF_F);
  const unsigned short* __restrict__ ElG = (const unsigned short*)(out + EL_OFF_F);

  const int tid = threadIdx.x;
  const int lane = tid & 63, wave = tid >> 6;
  const int bid = blockIdx.x;
  const int xcd = bid & 7;
  const int slot = bid >> 3;
  const int bx = slot & 3;
  const int by = xcd * 128 + (slot >> 2);
  const int c0 = bx * TC;
  const int n0 = by * TM;

  const int wc = c0 + wave * 64;
  const int m = lane & 15;
  const int q = lane >> 4;

  f32x4 acc[4][4];
#pragma unroll
  for (int i = 0; i < 4; ++i)
#pragma unroll
    for (int t = 0; t < 4; ++t) acc[i][t] = (f32x4){0.f, 0.f, 0.f, 0.f};

  const int sn = lane;
  const int kg = wave;

  float xv[8];
  {
    const float* xp = X + (size_t)(kg * 8) * N_TOK + n0 + sn;
#pragma unroll
    for (int j = 0; j < 8; ++j) xv[j] = xp[(size_t)j * N_TOK];
  }

#pragma unroll 1
  for (int kb = 0; kb < D_DIM; kb += BK) {
    const int p = (kb >> 5) & 1;
    bf16x8 bh[4], bl[4];
#pragma unroll
    for (int t = 0; t < 4; ++t) {
      const size_t eoff = (size_t)(wc + t * 16 + m) * D_DIM + kb + q * 8;
      bh[t] = *(const bf16x8*)(EhG + eoff);
      bl[t] = *(const bf16x8*)(ElG + eoff);
    }
    unsigned short hh[8], ll[8];
#pragma unroll
    for (int j = 0; j < 8; ++j) {
      hh[j] = f2bf(xv[j]);
      ll[j] = f2bf(xv[j] - bf2f(hh[j]));
    }
    *(bf16x8*)&xhb[p][sn * XS + kg * 8] = *(bf16x8*)hh;
    *(bf16x8*)&xlb[p][sn * XS + kg * 8] = *(bf16x8*)ll;
    if (kb + BK < D_DIM) {
      const float* xp = X + (size_t)(kb + BK + kg * 8) * N_TOK + n0 + sn;
#pragma unroll
      for (int j = 0; j < 8; ++j) xv[j] = xp[(size_t)j * N_TOK];
    }
    __syncthreads();
    bf16x8 ah[4], al[4];
#pragma unroll
    for (int i = 0; i < 4; ++i) {
      const int ro = (i * 16 + m) * XS + q * 8;
      ah[i] = *(const bf16x8*)&xhb[p][ro];
      al[i] = *(const bf16x8*)&xlb[p][ro];
    }
#pragma unroll
    for (int i = 0; i < 4; ++i)
#pragma unroll
      for (int t = 0; t < 4; ++t) {
        acc[i][t] = __builtin_amdgcn_mfma_f32_16x16x32_bf16(ah[i], bh[t], acc[i][t], 0, 0, 0);
        acc[i][t] = __builtin_amdgcn_mfma_f32_16x16x32_bf16(ah[i], bl[t], acc[i][t], 0, 0, 0);
        acc[i][t] = __builtin_amdgcn_mfma_f32_16x16x32_bf16(al[i], bh[t], acc[i][t], 0, 0, 0);
      }
  }

  float e2v[4];
#pragma unroll
  for (int t = 0; t < 4; ++t) e2v[t] = out[E2_OFF_F + wc + t * 16 + m];

#pragma unroll
  for (int i = 0; i < 4; ++i) {
#pragma unroll
    for (int r = 0; r < 4; ++r) {
      const int tok = n0 + i * 16 + q * 4 + r;
      const float x2v = out[IDX_OFF + tok];
      const size_t row = DIST_OFF + (size_t)tok * C_NUM;
#pragma unroll
      for (int t = 0; t < 4; ++t) {
        float d2 = fmaf(-2.0f, acc[i][t][r], x2v + e2v[t]);
        d2 = fmaxf(d2, 0.0f);
        out[row + wc + t * 16 + m] = -sqrtf(d2);
      }
    }
  }
}

__global__ __launch_bounds__(256) void k3_argmax(const float* __restrict__ X,
                                                 const float* __restrict__ E,
                                                 float* __restrict__ out) {
  __shared__ float lsum[4];
  const int tid = threadIdx.x, lane = tid & 63, w = tid >> 6;
  float wloss = 0.0f;

#pragma unroll 1
  for (int it = 0; it < 4; ++it) {
    const int n = blockIdx.x * 16 + w * 4 + it;
    const float* row = out + DIST_OFF + (size_t)n * C_NUM;

    float v[16];
    float best = -3.4e38f;
    int bi = 0x7fffffff;
#pragma unroll
    for (int j = 0; j < 16; ++j) {
      v[j] = row[j * 64 + lane];
      if (v[j] > best) { best = v[j]; bi = j * 64 + lane; }
    }
#pragma unroll
    for (int off = 32; off; off >>= 1) {
      const float ov = __shfl_xor(best, off, 64);
      const int oi = __shfl_xor(bi, off, 64);
      if (ov > best || (ov == best && oi < bi)) { best = ov; bi = oi; }
    }
    const float thr = best - MARGIN;
    unsigned long long masks[16];
    int total = 0;
#pragma unroll
    for (int j = 0; j < 16; ++j) {
      masks[j] = __ballot(v[j] > thr);
      total += __popcll(masks[j]);
    }
    float best_d2 = best * best;
    int best_idx = bi;
    if (total > 1) {
      best_d2 = 3.4e38f;
      best_idx = 0x7fffffff;
      for (int j = 0; j < 16; ++j) {
        unsigned long long mm = masks[j];
        while (mm) {
          const int l = __ffsll((long long)mm) - 1;
          mm &= mm - 1;
          const int c = j * 64 + l;
          float sx = 0.f, se = 0.f, sxe = 0.f;
#pragma unroll
          for (int r = 0; r < 4; ++r) {
            const int d = r * 64 + lane;
            const float xv = X[(size_t)d * N_TOK + n];
            const float ev = E[(size_t)c * D_DIM + d];
            sx = fmaf(xv, xv, sx);
            se = fmaf(ev, ev, se);
            sxe = fmaf(xv, ev, sxe);
          }
          float d2 = fmaf(-2.f, sxe, sx + se);
#pragma unroll
          for (int off = 32; off; off >>= 1) d2 += __shfl_xor(d2, off, 64);
          d2 = fmaxf(d2, 0.f);
          if (d2 < best_d2 || (d2 == best_d2 && c < best_idx)) {
            best_d2 = d2; best_idx = c;
          }
        }
      }
    }
    if (lane == 0) out[IDX_OFF + n] = (float)best_idx;
    wloss += best_d2;
  }
  if (lane == 0) lsum[w] = wloss;
  __syncthreads();
  if (tid == 0)
    out[PART_OFF_F + blockIdx.x] = lsum[0] + lsum[1] + lsum[2] + lsum[3];
}

__global__ __launch_bounds__(256) void k3b_loss(float* __restrict__ out) {
  __shared__ float red[4];
  const int tid = threadIdx.x, lane = tid & 63, w = tid >> 6;
  float s = 0.0f;
#pragma unroll
  for (int i = 0; i < NPART / 256; ++i) s += out[PART_OFF_F + i * 256 + tid];
#pragma unroll
  for (int off = 32; off; off >>= 1) s += __shfl_down(s, off, 64);
  if (lane == 0) red[w] = s;
  __syncthreads();
  if (tid == 0)
    out[LOSS_OFF] = (red[0] + red[1] + red[2] + red[3]) *
                    (0.25f / ((float)N_TOK * (float)D_DIM));
}

// ---------------------------------------------------------------------------
// k4: shared by both paths. out[d][n] = E[idx[n]][d].
// ---------------------------------------------------------------------------
__global__ __launch_bounds__(256) void k4_gather(const float* __restrict__ E,
                                                 float* __restrict__ out) {
  const int g = blockIdx.x * 256 + threadIdx.x;
  const int n = g * 4;
  const int i0 = (int)out[IDX_OFF + n + 0];
  const int i1 = (int)out[IDX_OFF + n + 1];
  const int i2 = (int)out[IDX_OFF + n + 2];
  const int i3 = (int)out[IDX_OFF + n + 3];
  const float* e0 = E + (size_t)i0 * D_DIM;
  const float* e1 = E + (size_t)i1 * D_DIM;
  const float* e2 = E + (size_t)i2 * D_DIM;
  const float* e3 = E + (size_t)i3 * D_DIM;
  const int d0 = blockIdx.y * 32;
#pragma unroll 4
  for (int d = d0; d < d0 + 32; ++d) {
    float4 wv = make_float4(e0[d], e1[d], e2[d], e3[d]);
    *(float4*)&out[(size_t)d * N_TOK + n] = wv;
  }
}

extern "C" void kernel_launch(void* const* d_in, const int* in_sizes, int n_in,
                              void* d_out, int out_size, void* d_ws, size_t ws_size,
                              hipStream_t stream) {
  const float* X = (const float*)d_in[0];   // (1, 256, 65536)
  const float* E = (const float*)d_in[1];   // (1, 1024, 256)
  float* out = (float*)d_out;

  if (ws_size >= WS_NEEDED && d_ws != nullptr) {
    unsigned char* ws = (unsigned char*)d_ws;
    hipLaunchKernelGGL(kA2_prep, dim3(1296), dim3(256), 0, stream, X, E, out, ws);
    hipLaunchKernelGGL(k2c_dist, dim3((C_NUM / TC) * (N_TOK / TM)), dim3(256), 0,
                       stream, out, ws);
    hipLaunchKernelGGL(k3a2_argmax, dim3(N_TOK / 16), dim3(256), 0, stream,
                       X, E, out, ws);
    hipLaunchKernelGGL(k3b2_loss, dim3(1), dim3(256), 0, stream, out, ws);
    hipLaunchKernelGGL(k4_gather, dim3(N_TOK / 4 / 256, 8), dim3(256), 0, stream,
                       E, out);
  } else {
    hipLaunchKernelGGL(kA_prep, dim3(272), dim3(256), 0, stream, X, E, out);
    hipLaunchKernelGGL(k2_dist, dim3((C_NUM / TC) * (N_TOK / TM)), dim3(256), 0,
                       stream, X, out);
    hipLaunchKernelGGL(k3_argmax, dim3(N_TOK / 16), dim3(256), 0, stream, X, E, out);
    hipLaunchKernelGGL(k3b_loss, dim3(1), dim3(256), 0, stream, out);
    hipLaunchKernelGGL(k4_gather, dim3(N_TOK / 4 / 256, 8), dim3(256), 0, stream,
                       E, out);
  }
}

// Round 7
// 641.696 us; speedup vs baseline: 1.0924x; 1.0924x over previous
//
#include <hip/hip_runtime.h>
#include <math.h>

#define N_TOK 65536
#define D_DIM 256
#define C_NUM 1024

// d_out layout (floats): out (D*N) | indices (N) | loss (1) | distances (N*C)
#define OUT_OFF   0
#define IDX_OFF   (D_DIM * N_TOK)            // 16777216
#define LOSS_OFF  (IDX_OFF + N_TOK)          // 16842752
#define DIST_OFF  (LOSS_OFF + 1)             // 16842753

#define MARGIN 0.01f
#define NPART 4096

typedef __attribute__((ext_vector_type(8))) short bf16x8;
typedef __attribute__((ext_vector_type(4))) float f32x4;

static __device__ __forceinline__ unsigned short f2bf(float f) {
  unsigned int u = __float_as_uint(f);
  unsigned int r = (u + 0x7fffu + ((u >> 16) & 1u)) >> 16;
  return (unsigned short)r;
}
static __device__ __forceinline__ float bf2f(unsigned short h) {
  return __uint_as_float(((unsigned int)h) << 16);
}

// ===========================================================================
// PATH A (ws_size >= WS_NEEDED):
//   out region (64MB, dead until k4) holds Xh (32MB) | Xl (32MB), [n][k] bf16.
//   x2 lives in IDX region (overwritten by k3a3's indices later).
//   ws: Eh | El | e2 | loss partials | per-(token,group) best-VALUE records.
// Round-7: k2c main loop/staging = round-4 config VERBATIM (measured 225us).
// Epilogue adds only a value-only group-best record (~12 ops/instance vs
// ~45 for R5/R6's val+idx+cnt chains, which cost ~90us). k3a3 reads the 16
// vals (64B/token); only groups with val > best-MARGIN can contain margin
// candidates (group max > thr <=> >=1 candidate), so it scans just those
// rows (256B each, usually one) — provably identical winner/total/loss to
// the round-1 full-row algorithm.
// ===========================================================================

// ws byte offsets
#define WS_EH   0                            // u16[1024*256]   512KB
#define WS_EL   524288                       // u16[1024*256]   512KB
#define WS_E2   1048576                      // f32[1024]       4KB
#define WS_PART 1052672                      // f32[4096]       16KB
#define WS_TP   1069056                      // f32[65536*16]   4MB
#define WS_NEEDED (WS_TP + (size_t)N_TOK * 16 * 4)

// Xh/Xl float offsets inside out region
#define XH_OFF_F 0
#define XL_OFF_F 8388608

// loss partials float offset (path B only; inside dead region)
#define PART_OFF_F 263168

// ---------------------------------------------------------------------------
// kA2: bid<1024: transpose+convert X -> Xh/Xl [n][k] (64 tokens per block).
//      1024..1039: convert E -> Eh/El + e2 (in ws).
//      1040..1295: x2[n] -> IDX region (verbatim old order -> bitwise same).
// ---------------------------------------------------------------------------
__global__ __launch_bounds__(256) void kA2_prep(const float* __restrict__ X,
                                                const float* __restrict__ E,
                                                float* __restrict__ out,
                                                unsigned char* __restrict__ ws) {
  const int bid = blockIdx.x, tid = threadIdx.x;
  if (bid < 1024) {
    // X transpose+convert: thread owns token n, d-segment sg (16 d's/chunk)
    unsigned short* XhG = (unsigned short*)(out + XH_OFF_F);
    unsigned short* XlG = (unsigned short*)(out + XL_OFF_F);
    const int n = bid * 64 + (tid >> 2);
    const int sg = (tid & 3) * 16;
    unsigned short* xh = XhG + (size_t)n * D_DIM;
    unsigned short* xl = XlG + (size_t)n * D_DIM;
#pragma unroll 1
    for (int dc = 0; dc < D_DIM; dc += 64) {
      float v[16];
#pragma unroll
      for (int j = 0; j < 16; ++j) v[j] = X[(size_t)(dc + sg + j) * N_TOK + n];
      unsigned short hh[16], ll[16];
#pragma unroll
      for (int j = 0; j < 16; ++j) {
        hh[j] = f2bf(v[j]);
        ll[j] = f2bf(v[j] - bf2f(hh[j]));
      }
      *(bf16x8*)(xh + dc + sg) = *(bf16x8*)&hh[0];
      *(bf16x8*)(xh + dc + sg + 8) = *(bf16x8*)&hh[8];
      *(bf16x8*)(xl + dc + sg) = *(bf16x8*)&ll[0];
      *(bf16x8*)(xl + dc + sg + 8) = *(bf16x8*)&ll[8];
    }
  } else if (bid < 1040) {
    unsigned short* EhG = (unsigned short*)(ws + WS_EH);
    unsigned short* ElG = (unsigned short*)(ws + WS_EL);
    float* e2p = (float*)(ws + WS_E2);
    const int lane = tid & 63, w = tid >> 6;
#pragma unroll 1
    for (int cc = 0; cc < 16; ++cc) {
      const int c = (bid - 1024) * 64 + w * 16 + cc;
      const float4 v = *(const float4*)(E + (size_t)c * D_DIM + lane * 4);
      unsigned short h0 = f2bf(v.x), h1 = f2bf(v.y), h2 = f2bf(v.z), h3 = f2bf(v.w);
      unsigned short l0 = f2bf(v.x - bf2f(h0)), l1 = f2bf(v.y - bf2f(h1));
      unsigned short l2 = f2bf(v.z - bf2f(h2)), l3 = f2bf(v.w - bf2f(h3));
      ushort4 hv = make_ushort4(h0, h1, h2, h3);
      ushort4 lv = make_ushort4(l0, l1, l2, l3);
      *(ushort4*)(EhG + (size_t)c * D_DIM + lane * 4) = hv;
      *(ushort4*)(ElG + (size_t)c * D_DIM + lane * 4) = lv;
      float s = v.x * v.x + v.y * v.y + v.z * v.z + v.w * v.w;
#pragma unroll
      for (int off = 32; off; off >>= 1) s += __shfl_down(s, off, 64);
      if (lane == 0) e2p[c] = s;
    }
  } else {
    const int n = (bid - 1040) * 256 + tid;
    float s = 0.0f;
#pragma unroll 8
    for (int d = 0; d < D_DIM; ++d) {
      float v = X[(size_t)d * N_TOK + n];
      s = fmaf(v, v, s);
    }
    out[IDX_OFF + n] = s;                    // x2 scratch (k3a3 overwrites later)
  }
}

// ---------------------------------------------------------------------------
// k2c: round-4 config verbatim (stage-once Xh+Xl LDS, one barrier, rolled
// unroll-2 loop) + value-only record epilogue.
// Block = 64 tokens x 256 codes, 4 waves; wave w owns 64 codes.
// ---------------------------------------------------------------------------
#define TM 64
#define TC 256
#define BK 32
#define XS2 264   // u16 row stride (256 + 8 pad); 528B, 16B-aligned

__global__ __launch_bounds__(256) void k2c_dist(float* __restrict__ out,
                                                unsigned char* __restrict__ ws) {
  __shared__ __align__(16) unsigned short xh[TM * XS2];
  __shared__ __align__(16) unsigned short xl[TM * XS2];

  const unsigned short* __restrict__ XhG = (const unsigned short*)(out + XH_OFF_F);
  const unsigned short* __restrict__ XlG = (const unsigned short*)(out + XL_OFF_F);
  const unsigned short* __restrict__ EhG = (const unsigned short*)(ws + WS_EH);
  const float* __restrict__ e2p = (const float*)(ws + WS_E2);
  float* __restrict__ tpv = (float*)(ws + WS_TP);

  const int tid = threadIdx.x;
  const int lane = tid & 63, wave = tid >> 6;

  // XCD-swizzled decode (4 code-tiles of a token-tile land on the same XCD)
  const int bid = blockIdx.x;
  const int xcd = bid & 7;
  const int slot = bid >> 3;
  const int bx = slot & 3;
  const int by = xcd * 128 + (slot >> 2);
  const int c0 = bx * TC;
  const int n0 = by * TM;

  const int wc = c0 + wave * 64;
  const int m = lane & 15;
  const int q = lane >> 4;

  // ---- stage whole A-tile once: thread owns token tl, 64-u16 segment ----
  {
    const int tl = tid >> 2;
    const int seg = (tid & 3) * 64;
    const unsigned short* gh = XhG + (size_t)(n0 + tl) * D_DIM + seg;
    const unsigned short* gl = XlG + (size_t)(n0 + tl) * D_DIM + seg;
    unsigned short* sh = xh + tl * XS2 + seg;
    unsigned short* sl = xl + tl * XS2 + seg;
#pragma unroll
    for (int j = 0; j < 8; ++j) {
      *(bf16x8*)(sh + j * 8) = *(const bf16x8*)(gh + j * 8);
      *(bf16x8*)(sl + j * 8) = *(const bf16x8*)(gl + j * 8);
    }
  }
  __syncthreads();   // the only barrier in this kernel

  f32x4 acc[4][4];
#pragma unroll
  for (int i = 0; i < 4; ++i)
#pragma unroll
    for (int t = 0; t < 4; ++t) acc[i][t] = (f32x4){0.f, 0.f, 0.f, 0.f};

  // hoisted B fragment base pointers (row*256 + q*8), offset by kb in loop
  const unsigned short* bp[4];
#pragma unroll
  for (int t = 0; t < 4; ++t) bp[t] = EhG + (size_t)(wc + t * 16 + m) * D_DIM + q * 8;
  const size_t loEu = (size_t)(WS_EL - WS_EH) / 2;        // u16 delta Eh->El

#pragma unroll 2
  for (int kb = 0; kb < D_DIM; kb += BK) {
    bf16x8 ah[4], al[4], bh[4], bl[4];
#pragma unroll
    for (int t = 0; t < 4; ++t) {
      bh[t] = *(const bf16x8*)(bp[t] + kb);
      bl[t] = *(const bf16x8*)(bp[t] + loEu + kb);
    }
#pragma unroll
    for (int i = 0; i < 4; ++i) {
      const int ro = (i * 16 + m) * XS2 + kb + q * 8;
      ah[i] = *(const bf16x8*)&xh[ro];
      al[i] = *(const bf16x8*)&xl[ro];
    }
#pragma unroll
    for (int i = 0; i < 4; ++i)
#pragma unroll
      for (int t = 0; t < 4; ++t) {
        acc[i][t] = __builtin_amdgcn_mfma_f32_16x16x32_bf16(ah[i], bh[t], acc[i][t], 0, 0, 0);
        acc[i][t] = __builtin_amdgcn_mfma_f32_16x16x32_bf16(ah[i], bl[t], acc[i][t], 0, 0, 0);
        acc[i][t] = __builtin_amdgcn_mfma_f32_16x16x32_bf16(al[i], bh[t], acc[i][t], 0, 0, 0);
      }
  }

  // ---- epilogue: distances + value-only group-best record ----
  float e2v[4];
#pragma unroll
  for (int t = 0; t < 4; ++t) e2v[t] = e2p[wc + t * 16 + m];

#pragma unroll
  for (int i = 0; i < 4; ++i) {
#pragma unroll
    for (int r = 0; r < 4; ++r) {
      const int tok = n0 + i * 16 + q * 4 + r;
      const float x2v = out[IDX_OFF + tok];
      const size_t row = DIST_OFF + (size_t)tok * C_NUM;
      float bestv = -3.4e38f;
#pragma unroll
      for (int t = 0; t < 4; ++t) {
        float d2 = fmaf(-2.0f, acc[i][t][r], x2v + e2v[t]);
        d2 = fmaxf(d2, 0.0f);
        const float dd = -sqrtf(d2);
        out[row + wc + t * 16 + m] = dd;
        bestv = fmaxf(bestv, dd);
      }
      // group max across the 16 m-lanes (stays within the q-group: off<16)
#pragma unroll
      for (int off = 1; off < 16; off <<= 1)
        bestv = fmaxf(bestv, __shfl_xor(bestv, off, 64));
      if ((lane & 15) == 0)
        tpv[(size_t)tok * 16 + bx * 4 + wave] = bestv;
    }
  }
}

// ---------------------------------------------------------------------------
// k3a3: wave per token (4 tokens/wave, 4 waves/block). Read 16 group-best
// vals (64B); flagged groups (val > best-MARGIN) are exactly those containing
// margin candidates. Scan only flagged rows (256B each): lex-argmax +
// candidate count over the same candidate set as the round-1 full-row scan.
// total==1 -> winner/loss from approx row; else exact fp32 recompute over
// candidates (verbatim round-1 slow path). Output identical to round-1 k3.
// ---------------------------------------------------------------------------
__global__ __launch_bounds__(256) void k3a3_argmax(const float* __restrict__ X,
                                                   const float* __restrict__ E,
                                                   float* __restrict__ out,
                                                   unsigned char* __restrict__ ws) {
  const float* __restrict__ tpv = (const float*)(ws + WS_TP);
  float* __restrict__ part = (float*)(ws + WS_PART);
  __shared__ float lsum[4];
  const int tid = threadIdx.x, lane = tid & 63, w = tid >> 6;
  float wloss = 0.0f;

#pragma unroll 1
  for (int it = 0; it < 4; ++it) {
    const int n = blockIdx.x * 16 + w * 4 + it;
    const float* row = out + DIST_OFF + (size_t)n * C_NUM;

    // 16 group-best values (lanes 16-63 mirror lanes 0-15)
    const float gval = tpv[(size_t)n * 16 + (lane & 15)];
    float best = gval;
#pragma unroll
    for (int off = 1; off < 16; off <<= 1)
      best = fmaxf(best, __shfl_xor(best, off, 64));
    const float thr = best - MARGIN;
    const unsigned fmask = (unsigned)(__ballot(gval > thr) & 0xffffull);

    // scan flagged groups: lex-argmax + candidate count (same set as full-row)
    float bestv = -3.4e38f;
    int bi = 0x7fffffff;
    int total = 0;
    unsigned fm = fmask;
    while (fm) {
      const int j = __ffs(fm) - 1;
      fm &= fm - 1;
      const float v = row[j * 64 + lane];
      float bv = v;
      int bix = j * 64 + lane;
#pragma unroll
      for (int off = 32; off; off >>= 1) {
        const float ov = __shfl_xor(bv, off, 64);
        const int oi = __shfl_xor(bix, off, 64);
        if (ov > bv || (ov == bv && oi < bix)) { bv = ov; bix = oi; }
      }
      if (bv > bestv || (bv == bestv && bix < bi)) { bestv = bv; bi = bix; }
      total += __popcll(__ballot(v > thr));
    }

    if (total == 1) {
      if (lane == 0) out[IDX_OFF + n] = (float)bi;
      wloss += bestv * bestv;
    } else {
      // exact fp32 recompute over candidates (all lie in flagged groups)
      float best_d2 = 3.4e38f;
      int best_idx = 0x7fffffff;
      unsigned fm2 = fmask;
      while (fm2) {
        const int j = __ffs(fm2) - 1;
        fm2 &= fm2 - 1;
        const float v = row[j * 64 + lane];
        unsigned long long mm = __ballot(v > thr);
        while (mm) {
          const int l = __ffsll((long long)mm) - 1;
          mm &= mm - 1;
          const int c = j * 64 + l;
          float sx = 0.f, se = 0.f, sxe = 0.f;
#pragma unroll
          for (int r = 0; r < 4; ++r) {
            const int d = r * 64 + lane;
            const float xv = X[(size_t)d * N_TOK + n];
            const float ev = E[(size_t)c * D_DIM + d];
            sx = fmaf(xv, xv, sx);
            se = fmaf(ev, ev, se);
            sxe = fmaf(xv, ev, sxe);
          }
          float d2 = fmaf(-2.f, sxe, sx + se);
#pragma unroll
          for (int off = 32; off; off >>= 1) d2 += __shfl_xor(d2, off, 64);
          d2 = fmaxf(d2, 0.f);
          if (d2 < best_d2 || (d2 == best_d2 && c < best_idx)) {
            best_d2 = d2; best_idx = c;
          }
        }
      }
      if (lane == 0) out[IDX_OFF + n] = (float)best_idx;
      wloss += best_d2;
    }
  }
  if (lane == 0) lsum[w] = wloss;
  __syncthreads();
  if (tid == 0)
    part[blockIdx.x] = lsum[0] + lsum[1] + lsum[2] + lsum[3];
}

__global__ __launch_bounds__(256) void k3b2_loss(float* __restrict__ out,
                                                 unsigned char* __restrict__ ws) {
  const float* __restrict__ part = (const float*)(ws + WS_PART);
  __shared__ float red[4];
  const int tid = threadIdx.x, lane = tid & 63, w = tid >> 6;
  float s = 0.0f;
#pragma unroll
  for (int i = 0; i < NPART / 256; ++i) s += part[i * 256 + tid];
#pragma unroll
  for (int off = 32; off; off >>= 1) s += __shfl_down(s, off, 64);
  if (lane == 0) red[w] = s;
  __syncthreads();
  if (tid == 0)
    out[LOSS_OFF] = (red[0] + red[1] + red[2] + red[3]) *
                    (0.25f / ((float)N_TOK * (float)D_DIM));
}

// ===========================================================================
// PATH B (fallback, ws unusable): round-1 kernels verbatim.
// ===========================================================================
#define EH_OFF_F  0
#define EL_OFF_F  131072
#define E2_OFF_F  262144

__global__ __launch_bounds__(256) void kA_prep(const float* __restrict__ X,
                                               const float* __restrict__ E,
                                               float* __restrict__ out) {
  const int bid = blockIdx.x, tid = threadIdx.x;
  if (bid < 256) {
    const int n = bid * 256 + tid;
    float s = 0.0f;
#pragma unroll 8
    for (int d = 0; d < D_DIM; ++d) {
      float v = X[(size_t)d * N_TOK + n];
      s = fmaf(v, v, s);
    }
    out[IDX_OFF + n] = s;
  } else {
    unsigned short* EhG = (unsigned short*)(out + EH_OFF_F);
    unsigned short* ElG = (unsigned short*)(out + EL_OFF_F);
    const int lane = tid & 63, w = tid >> 6;
#pragma unroll 1
    for (int cc = 0; cc < 16; ++cc) {
      const int c = (bid - 256) * 64 + w * 16 + cc;
      const float4 v = *(const float4*)(E + (size_t)c * D_DIM + lane * 4);
      unsigned short h0 = f2bf(v.x), h1 = f2bf(v.y), h2 = f2bf(v.z), h3 = f2bf(v.w);
      unsigned short l0 = f2bf(v.x - bf2f(h0)), l1 = f2bf(v.y - bf2f(h1));
      unsigned short l2 = f2bf(v.z - bf2f(h2)), l3 = f2bf(v.w - bf2f(h3));
      ushort4 hv = make_ushort4(h0, h1, h2, h3);
      ushort4 lv = make_ushort4(l0, l1, l2, l3);
      *(ushort4*)(EhG + (size_t)c * D_DIM + lane * 4) = hv;
      *(ushort4*)(ElG + (size_t)c * D_DIM + lane * 4) = lv;
      float s = v.x * v.x + v.y * v.y + v.z * v.z + v.w * v.w;
#pragma unroll
      for (int off = 32; off; off >>= 1) s += __shfl_down(s, off, 64);
      if (lane == 0) out[E2_OFF_F + c] = s;
    }
  }
}

#define XS 40

__global__ __launch_bounds__(256) void k2_dist(const float* __restrict__ X,
                                               float* __restrict__ out) {
  __shared__ __align__(16) unsigned short xhb[2][TM * XS];
  __shared__ __align__(16) unsigned short xlb[2][TM * XS];

  const unsigned short* __restrict__ EhG = (const unsigned short*)(out + EH_OFF_F);
  const unsigned short* __restrict__ ElG = (const unsigned short*)(out + EL_OFF_F);

  const int tid = threadIdx.x;
  const int lane = tid & 63, wave = tid >> 6;
  const int bid = blockIdx.x;
  const int xcd = bid & 7;
  const int slot = bid >> 3;
  const int bx = slot & 3;
  const int by = xcd * 128 + (slot >> 2);
  const int c0 = bx * TC;
  const int n0 = by * TM;

  const int wc = c0 + wave * 64;
  const int m = lane & 15;
  const int q = lane >> 4;

  f32x4 acc[4][4];
#pragma unroll
  for (int i = 0; i < 4; ++i)
#pragma unroll
    for (int t = 0; t < 4; ++t) acc[i][t] = (f32x4){0.f, 0.f, 0.f, 0.f};

  const int sn = lane;
  const int kg = wave;

  float xv[8];
  {
    const float* xp = X + (size_t)(kg * 8) * N_TOK + n0 + sn;
#pragma unroll
    for (int j = 0; j < 8; ++j) xv[j] = xp[(size_t)j * N_TOK];
  }

#pragma unroll 1
  for (int kb = 0; kb < D_DIM; kb += BK) {
    const int p = (kb >> 5) & 1;
    bf16x8 bh[4], bl[4];
#pragma unroll
    for (int t = 0; t < 4; ++t) {
      const size_t eoff = (size_t)(wc + t * 16 + m) * D_DIM + kb + q * 8;
      bh[t] = *(const bf16x8*)(EhG + eoff);
      bl[t] = *(const bf16x8*)(ElG + eoff);
    }
    unsigned short hh[8], ll[8];
#pragma unroll
    for (int j = 0; j < 8; ++j) {
      hh[j] = f2bf(xv[j]);
      ll[j] = f2bf(xv[j] - bf2f(hh[j]));
    }
    *(bf16x8*)&xhb[p][sn * XS + kg * 8] = *(bf16x8*)hh;
    *(bf16x8*)&xlb[p][sn * XS + kg * 8] = *(bf16x8*)ll;
    if (kb + BK < D_DIM) {
      const float* xp = X + (size_t)(kb + BK + kg * 8) * N_TOK + n0 + sn;
#pragma unroll
      for (int j = 0; j < 8; ++j) xv[j] = xp[(size_t)j * N_TOK];
    }
    __syncthreads();
    bf16x8 ah[4], al[4];
#pragma unroll
    for (int i = 0; i < 4; ++i) {
      const int ro = (i * 16 + m) * XS + q * 8;
      ah[i] = *(const bf16x8*)&xhb[p][ro];
      al[i] = *(const bf16x8*)&xlb[p][ro];
    }
#pragma unroll
    for (int i = 0; i < 4; ++i)
#pragma unroll
      for (int t = 0; t < 4; ++t) {
        acc[i][t] = __builtin_amdgcn_mfma_f32_16x16x32_bf16(ah[i], bh[t], acc[i][t], 0, 0, 0);
        acc[i][t] = __builtin_amdgcn_mfma_f32_16x16x32_bf16(ah[i], bl[t], acc[i][t], 0, 0, 0);
        acc[i][t] = __builtin_amdgcn_mfma_f32_16x16x32_bf16(al[i], bh[t], acc[i][t], 0, 0, 0);
      }
  }

  float e2v[4];
#pragma unroll
  for (int t = 0; t < 4; ++t) e2v[t] = out[E2_OFF_F + wc + t * 16 + m];

#pragma unroll
  for (int i = 0; i < 4; ++i) {
#pragma unroll
    for (int r = 0; r < 4; ++r) {
      const int tok = n0 + i * 16 + q * 4 + r;
      const float x2v = out[IDX_OFF + tok];
      const size_t row = DIST_OFF + (size_t)tok * C_NUM;
#pragma unroll
      for (int t = 0; t < 4; ++t) {
        float d2 = fmaf(-2.0f, acc[i][t][r], x2v + e2v[t]);
        d2 = fmaxf(d2, 0.0f);
        out[row + wc + t * 16 + m] = -sqrtf(d2);
      }
    }
  }
}

__global__ __launch_bounds__(256) void k3_argmax(const float* __restrict__ X,
                                                 const float* __restrict__ E,
                                                 float* __restrict__ out) {
  __shared__ float lsum[4];
  const int tid = threadIdx.x, lane = tid & 63, w = tid >> 6;
  float wloss = 0.0f;

#pragma unroll 1
  for (int it = 0; it < 4; ++it) {
    const int n = blockIdx.x * 16 + w * 4 + it;
    const float* row = out + DIST_OFF + (size_t)n * C_NUM;

    float v[16];
    float best = -3.4e38f;
    int bi = 0x7fffffff;
#pragma unroll
    for (int j = 0; j < 16; ++j) {
      v[j] = row[j * 64 + lane];
      if (v[j] > best) { best = v[j]; bi = j * 64 + lane; }
    }
#pragma unroll
    for (int off = 32; off; off >>= 1) {
      const float ov = __shfl_xor(best, off, 64);
      const int oi = __shfl_xor(bi, off, 64);
      if (ov > best || (ov == best && oi < bi)) { best = ov; bi = oi; }
    }
    const float thr = best - MARGIN;
    unsigned long long masks[16];
    int total = 0;
#pragma unroll
    for (int j = 0; j < 16; ++j) {
      masks[j] = __ballot(v[j] > thr);
      total += __popcll(masks[j]);
    }
    float best_d2 = best * best;
    int best_idx = bi;
    if (total > 1) {
      best_d2 = 3.4e38f;
      best_idx = 0x7fffffff;
      for (int j = 0; j < 16; ++j) {
        unsigned long long mm = masks[j];
        while (mm) {
          const int l = __ffsll((long long)mm) - 1;
          mm &= mm - 1;
          const int c = j * 64 + l;
          float sx = 0.f, se = 0.f, sxe = 0.f;
#pragma unroll
          for (int r = 0; r < 4; ++r) {
            const int d = r * 64 + lane;
            const float xv = X[(size_t)d * N_TOK + n];
            const float ev = E[(size_t)c * D_DIM + d];
            sx = fmaf(xv, xv, sx);
            se = fmaf(ev, ev, se);
            sxe = fmaf(xv, ev, sxe);
          }
          float d2 = fmaf(-2.f, sxe, sx + se);
#pragma unroll
          for (int off = 32; off; off >>= 1) d2 += __shfl_xor(d2, off, 64);
          d2 = fmaxf(d2, 0.f);
          if (d2 < best_d2 || (d2 == best_d2 && c < best_idx)) {
            best_d2 = d2; best_idx = c;
          }
        }
      }
    }
    if (lane == 0) out[IDX_OFF + n] = (float)best_idx;
    wloss += best_d2;
  }
  if (lane == 0) lsum[w] = wloss;
  __syncthreads();
  if (tid == 0)
    out[PART_OFF_F + blockIdx.x] = lsum[0] + lsum[1] + lsum[2] + lsum[3];
}

__global__ __launch_bounds__(256) void k3b_loss(float* __restrict__ out) {
  __shared__ float red[4];
  const int tid = threadIdx.x, lane = tid & 63, w = tid >> 6;
  float s = 0.0f;
#pragma unroll
  for (int i = 0; i < NPART / 256; ++i) s += out[PART_OFF_F + i * 256 + tid];
#pragma unroll
  for (int off = 32; off; off >>= 1) s += __shfl_down(s, off, 64);
  if (lane == 0) red[w] = s;
  __syncthreads();
  if (tid == 0)
    out[LOSS_OFF] = (red[0] + red[1] + red[2] + red[3]) *
                    (0.25f / ((float)N_TOK * (float)D_DIM));
}

// ---------------------------------------------------------------------------
// k4: shared by both paths. out[d][n] = E[idx[n]][d].
// ---------------------------------------------------------------------------
__global__ __launch_bounds__(256) void k4_gather(const float* __restrict__ E,
                                                 float* __restrict__ out) {
  const int g = blockIdx.x * 256 + threadIdx.x;
  const int n = g * 4;
  const int i0 = (int)out[IDX_OFF + n + 0];
  const int i1 = (int)out[IDX_OFF + n + 1];
  const int i2 = (int)out[IDX_OFF + n + 2];
  const int i3 = (int)out[IDX_OFF + n + 3];
  const float* e0 = E + (size_t)i0 * D_DIM;
  const float* e1 = E + (size_t)i1 * D_DIM;
  const float* e2 = E + (size_t)i2 * D_DIM;
  const float* e3 = E + (size_t)i3 * D_DIM;
  const int d0 = blockIdx.y * 32;
#pragma unroll 4
  for (int d = d0; d < d0 + 32; ++d) {
    float4 wv = make_float4(e0[d], e1[d], e2[d], e3[d]);
    *(float4*)&out[(size_t)d * N_TOK + n] = wv;
  }
}

extern "C" void kernel_launch(void* const* d_in, const int* in_sizes, int n_in,
                              void* d_out, int out_size, void* d_ws, size_t ws_size,
                              hipStream_t stream) {
  const float* X = (const float*)d_in[0];   // (1, 256, 65536)
  const float* E = (const float*)d_in[1];   // (1, 1024, 256)
  float* out = (float*)d_out;

  if (ws_size >= WS_NEEDED && d_ws != nullptr) {
    unsigned char* ws = (unsigned char*)d_ws;
    hipLaunchKernelGGL(kA2_prep, dim3(1296), dim3(256), 0, stream, X, E, out, ws);
    hipLaunchKernelGGL(k2c_dist, dim3((C_NUM / TC) * (N_TOK / TM)), dim3(256), 0,
                       stream, out, ws);
    hipLaunchKernelGGL(k3a3_argmax, dim3(N_TOK / 16), dim3(256), 0, stream,
                       X, E, out, ws);
    hipLaunchKernelGGL(k3b2_loss, dim3(1), dim3(256), 0, stream, out, ws);
    hipLaunchKernelGGL(k4_gather, dim3(N_TOK / 4 / 256, 8), dim3(256), 0, stream,
                       E, out);
  } else {
    hipLaunchKernelGGL(kA_prep, dim3(272), dim3(256), 0, stream, X, E, out);
    hipLaunchKernelGGL(k2_dist, dim3((C_NUM / TC) * (N_TOK / TM)), dim3(256), 0,
                       stream, X, out);
    hipLaunchKernelGGL(k3_argmax, dim3(N_TOK / 16), dim3(256), 0, stream, X, E, out);
    hipLaunchKernelGGL(k3b_loss, dim3(1), dim3(256), 0, stream, out);
    hipLaunchKernelGGL(k4_gather, dim3(N_TOK / 4 / 256, 8), dim3(256), 0, stream,
                       E, out);
  }
}

// Round 8
// 614.424 us; speedup vs baseline: 1.1409x; 1.0444x over previous
//
#include <hip/hip_runtime.h>
#include <math.h>

#define N_TOK 65536
#define D_DIM 256
#define C_NUM 1024

// d_out layout (floats): out (D*N) | indices (N) | loss (1) | distances (N*C)
#define OUT_OFF   0
#define IDX_OFF   (D_DIM * N_TOK)            // 16777216
#define LOSS_OFF  (IDX_OFF + N_TOK)          // 16842752
#define DIST_OFF  (LOSS_OFF + 1)             // 16842753

#define MARGIN 0.01f
#define NPART 4096

typedef __attribute__((ext_vector_type(8))) short bf16x8;
typedef __attribute__((ext_vector_type(4))) float f32x4;

static __device__ __forceinline__ unsigned short f2bf(float f) {
  unsigned int u = __float_as_uint(f);
  unsigned int r = (u + 0x7fffu + ((u >> 16) & 1u)) >> 16;
  return (unsigned short)r;
}
static __device__ __forceinline__ float bf2f(unsigned short h) {
  return __uint_as_float(((unsigned int)h) << 16);
}

// ===========================================================================
// PATH A (ws_size >= WS_NEEDED):
//   out region (64MB, dead until k4) holds Xh (32MB) | Xl (32MB), [n][k] bf16.
//   x2 lives in IDX region (overwritten by k3a4's indices later).
//   ws: Eh | El | e2 | loss partials | per-(token,group) best-VALUE records.
// Round-8 deltas vs round-7 (each independently low-risk):
//   kA2: x2 fused into transpose pass (X read ONCE; 4-lane shfl reduce).
//        x2 rounding differs ~1ulp but shifts a token's d2 uniformly ->
//        ordering/argmax invariant; distances shift ~1e-6.
//   k2c: 16 x2 + 4 e2 loads hoisted ABOVE the K-loop (before any aliasing
//        distance store) so their L2 latency hides under the main loop.
//   k3a4: k3a2's proven 4-tokens-per-wave concurrent structure on value-only
//        records; single-flagged-group fast path reads one float4/lane.
//        Gate nflag==1 && cnt==1 == round-1's total==1 exactly.
//   k4: indices loaded as float4.
// ===========================================================================

// ws byte offsets
#define WS_EH   0                            // u16[1024*256]   512KB
#define WS_EL   524288                       // u16[1024*256]   512KB
#define WS_E2   1048576                      // f32[1024]       4KB
#define WS_PART 1052672                      // f32[4096]       16KB
#define WS_TP   1069056                      // f32[65536*16]   4MB
#define WS_NEEDED (WS_TP + (size_t)N_TOK * 16 * 4)

// Xh/Xl float offsets inside out region
#define XH_OFF_F 0
#define XL_OFF_F 8388608

// loss partials float offset (path B only; inside dead region)
#define PART_OFF_F 263168

// ---------------------------------------------------------------------------
// kA2: bid<1024: transpose+convert X -> Xh/Xl [n][k] + fused x2 (64 tok/blk).
//      1024..1039: convert E -> Eh/El + e2 (in ws).
// ---------------------------------------------------------------------------
__global__ __launch_bounds__(256) void kA2_prep(const float* __restrict__ X,
                                                const float* __restrict__ E,
                                                float* __restrict__ out,
                                                unsigned char* __restrict__ ws) {
  const int bid = blockIdx.x, tid = threadIdx.x;
  if (bid < 1024) {
    // X transpose+convert: thread owns token n, d-segment sg (16 d's/chunk)
    unsigned short* XhG = (unsigned short*)(out + XH_OFF_F);
    unsigned short* XlG = (unsigned short*)(out + XL_OFF_F);
    const int n = bid * 64 + (tid >> 2);
    const int sg = (tid & 3) * 16;
    unsigned short* xh = XhG + (size_t)n * D_DIM;
    unsigned short* xl = XlG + (size_t)n * D_DIM;
    float s = 0.0f;
#pragma unroll 1
    for (int dc = 0; dc < D_DIM; dc += 64) {
      float v[16];
#pragma unroll
      for (int j = 0; j < 16; ++j) v[j] = X[(size_t)(dc + sg + j) * N_TOK + n];
      unsigned short hh[16], ll[16];
#pragma unroll
      for (int j = 0; j < 16; ++j) {
        s = fmaf(v[j], v[j], s);
        hh[j] = f2bf(v[j]);
        ll[j] = f2bf(v[j] - bf2f(hh[j]));
      }
      *(bf16x8*)(xh + dc + sg) = *(bf16x8*)&hh[0];
      *(bf16x8*)(xh + dc + sg + 8) = *(bf16x8*)&hh[8];
      *(bf16x8*)(xl + dc + sg) = *(bf16x8*)&ll[0];
      *(bf16x8*)(xl + dc + sg + 8) = *(bf16x8*)&ll[8];
    }
    // x2: reduce across the 4 consecutive lanes owning this token
    s += __shfl_xor(s, 1, 64);
    s += __shfl_xor(s, 2, 64);
    if ((tid & 3) == 0) out[IDX_OFF + n] = s;   // x2 scratch
  } else {
    unsigned short* EhG = (unsigned short*)(ws + WS_EH);
    unsigned short* ElG = (unsigned short*)(ws + WS_EL);
    float* e2p = (float*)(ws + WS_E2);
    const int lane = tid & 63, w = tid >> 6;
#pragma unroll 1
    for (int cc = 0; cc < 16; ++cc) {
      const int c = (bid - 1024) * 64 + w * 16 + cc;
      const float4 v = *(const float4*)(E + (size_t)c * D_DIM + lane * 4);
      unsigned short h0 = f2bf(v.x), h1 = f2bf(v.y), h2 = f2bf(v.z), h3 = f2bf(v.w);
      unsigned short l0 = f2bf(v.x - bf2f(h0)), l1 = f2bf(v.y - bf2f(h1));
      unsigned short l2 = f2bf(v.z - bf2f(h2)), l3 = f2bf(v.w - bf2f(h3));
      ushort4 hv = make_ushort4(h0, h1, h2, h3);
      ushort4 lv = make_ushort4(l0, l1, l2, l3);
      *(ushort4*)(EhG + (size_t)c * D_DIM + lane * 4) = hv;
      *(ushort4*)(ElG + (size_t)c * D_DIM + lane * 4) = lv;
      float s = v.x * v.x + v.y * v.y + v.z * v.z + v.w * v.w;
#pragma unroll
      for (int off = 32; off; off >>= 1) s += __shfl_down(s, off, 64);
      if (lane == 0) e2p[c] = s;
    }
  }
}

// ---------------------------------------------------------------------------
// k2c: stage-once Xh+Xl LDS, one barrier, rolled unroll-2 loop, x2/e2
// hoisted above the K-loop, value-only record epilogue.
// Block = 64 tokens x 256 codes, 4 waves; wave w owns 64 codes.
// ---------------------------------------------------------------------------
#define TM 64
#define TC 256
#define BK 32
#define XS2 264   // u16 row stride (256 + 8 pad); 528B, 16B-aligned

__global__ __launch_bounds__(256) void k2c_dist(float* __restrict__ out,
                                                unsigned char* __restrict__ ws) {
  __shared__ __align__(16) unsigned short xh[TM * XS2];
  __shared__ __align__(16) unsigned short xl[TM * XS2];

  const unsigned short* __restrict__ XhG = (const unsigned short*)(out + XH_OFF_F);
  const unsigned short* __restrict__ XlG = (const unsigned short*)(out + XL_OFF_F);
  const unsigned short* __restrict__ EhG = (const unsigned short*)(ws + WS_EH);
  const float* __restrict__ e2p = (const float*)(ws + WS_E2);
  float* __restrict__ tpv = (float*)(ws + WS_TP);

  const int tid = threadIdx.x;
  const int lane = tid & 63, wave = tid >> 6;

  // XCD-swizzled decode (4 code-tiles of a token-tile land on the same XCD)
  const int bid = blockIdx.x;
  const int xcd = bid & 7;
  const int slot = bid >> 3;
  const int bx = slot & 3;
  const int by = xcd * 128 + (slot >> 2);
  const int c0 = bx * TC;
  const int n0 = by * TM;

  const int wc = c0 + wave * 64;
  const int m = lane & 15;
  const int q = lane >> 4;

  // ---- stage whole A-tile once: thread owns token tl, 64-u16 segment ----
  {
    const int tl = tid >> 2;
    const int seg = (tid & 3) * 64;
    const unsigned short* gh = XhG + (size_t)(n0 + tl) * D_DIM + seg;
    const unsigned short* gl = XlG + (size_t)(n0 + tl) * D_DIM + seg;
    unsigned short* sh = xh + tl * XS2 + seg;
    unsigned short* sl = xl + tl * XS2 + seg;
#pragma unroll
    for (int j = 0; j < 8; ++j) {
      *(bf16x8*)(sh + j * 8) = *(const bf16x8*)(gh + j * 8);
      *(bf16x8*)(sl + j * 8) = *(const bf16x8*)(gl + j * 8);
    }
  }

  // ---- hoisted epilogue operands: issue loads before the long K-loop ----
  float x2r[16];
#pragma unroll
  for (int i = 0; i < 4; ++i)
#pragma unroll
    for (int r = 0; r < 4; ++r)
      x2r[i * 4 + r] = out[IDX_OFF + n0 + i * 16 + q * 4 + r];
  float e2v[4];
#pragma unroll
  for (int t = 0; t < 4; ++t) e2v[t] = e2p[wc + t * 16 + m];

  __syncthreads();   // the only barrier in this kernel

  f32x4 acc[4][4];
#pragma unroll
  for (int i = 0; i < 4; ++i)
#pragma unroll
    for (int t = 0; t < 4; ++t) acc[i][t] = (f32x4){0.f, 0.f, 0.f, 0.f};

  // hoisted B fragment base pointers (row*256 + q*8), offset by kb in loop
  const unsigned short* bp[4];
#pragma unroll
  for (int t = 0; t < 4; ++t) bp[t] = EhG + (size_t)(wc + t * 16 + m) * D_DIM + q * 8;
  const size_t loEu = (size_t)(WS_EL - WS_EH) / 2;        // u16 delta Eh->El

#pragma unroll 2
  for (int kb = 0; kb < D_DIM; kb += BK) {
    bf16x8 ah[4], al[4], bh[4], bl[4];
#pragma unroll
    for (int t = 0; t < 4; ++t) {
      bh[t] = *(const bf16x8*)(bp[t] + kb);
      bl[t] = *(const bf16x8*)(bp[t] + loEu + kb);
    }
#pragma unroll
    for (int i = 0; i < 4; ++i) {
      const int ro = (i * 16 + m) * XS2 + kb + q * 8;
      ah[i] = *(const bf16x8*)&xh[ro];
      al[i] = *(const bf16x8*)&xl[ro];
    }
#pragma unroll
    for (int i = 0; i < 4; ++i)
#pragma unroll
      for (int t = 0; t < 4; ++t) {
        acc[i][t] = __builtin_amdgcn_mfma_f32_16x16x32_bf16(ah[i], bh[t], acc[i][t], 0, 0, 0);
        acc[i][t] = __builtin_amdgcn_mfma_f32_16x16x32_bf16(ah[i], bl[t], acc[i][t], 0, 0, 0);
        acc[i][t] = __builtin_amdgcn_mfma_f32_16x16x32_bf16(al[i], bh[t], acc[i][t], 0, 0, 0);
      }
  }

  // ---- epilogue: distances + value-only group-best record ----
#pragma unroll
  for (int i = 0; i < 4; ++i) {
#pragma unroll
    for (int r = 0; r < 4; ++r) {
      const int tok = n0 + i * 16 + q * 4 + r;
      const float x2v = x2r[i * 4 + r];
      const size_t row = DIST_OFF + (size_t)tok * C_NUM;
      float bestv = -3.4e38f;
#pragma unroll
      for (int t = 0; t < 4; ++t) {
        float d2 = fmaf(-2.0f, acc[i][t][r], x2v + e2v[t]);
        d2 = fmaxf(d2, 0.0f);
        const float dd = -sqrtf(d2);
        out[row + wc + t * 16 + m] = dd;
        bestv = fmaxf(bestv, dd);
      }
      // group max across the 16 m-lanes (stays within the q-group: off<16)
#pragma unroll
      for (int off = 1; off < 16; off <<= 1)
        bestv = fmaxf(bestv, __shfl_xor(bestv, off, 64));
      if ((lane & 15) == 0)
        tpv[(size_t)tok * 16 + bx * 4 + wave] = bestv;
    }
  }
}

// ---------------------------------------------------------------------------
// k3a4: 4 tokens per wave CONCURRENTLY (16 lanes each; k3a2's proven shape).
// Read 16 group-best vals/token (one per lane). Flagged groups = those with
// val > best-MARGIN (group max > thr <=> group contains a candidate).
// Fast path (nflag==1): read that group's 64-dist slice (float4/lane),
// lex-argmax + candidate count in-segment; cnt==1 -> winner/loss (== round-1
// total==1 path exactly). Else: round-1 full-row algorithm verbatim,
// wave-serial over slow tokens (structure validated in round 5).
// ---------------------------------------------------------------------------
__global__ __launch_bounds__(256) void k3a4_argmax(const float* __restrict__ X,
                                                   const float* __restrict__ E,
                                                   float* __restrict__ out,
                                                   unsigned char* __restrict__ ws) {
  const float* __restrict__ tpv = (const float*)(ws + WS_TP);
  float* __restrict__ part = (float*)(ws + WS_PART);
  __shared__ float lsum[4];
  const int tid = threadIdx.x, lane = tid & 63, w = tid >> 6;
  const int g = lane & 15, seg = lane >> 4;
  const int n = blockIdx.x * 16 + w * 4 + seg;

  const float gval = tpv[(size_t)n * 16 + g];
  float best = gval;
#pragma unroll
  for (int off = 1; off < 16; off <<= 1)
    best = fmaxf(best, __shfl_xor(best, off, 64));
  const float thr = best - MARGIN;
  const unsigned long long bal = __ballot(gval > thr);
  const unsigned m16 = (unsigned)((bal >> (seg * 16)) & 0xffffull);
  const int nflag = __popc(m16);
  const int j = __ffs(m16) - 1;            // first flagged group (nflag >= 1)

  // read the flagged group's 64-distance slice: 16 lanes x float4 = 256B
  const float4 rv =
      *(const float4*)(out + DIST_OFF + (size_t)n * C_NUM + j * 64 + g * 4);

  // lex-argmax (max val, min idx) + candidate count within the group
  float bv = rv.x;
  int bix = j * 64 + g * 4;
  if (rv.y > bv) { bv = rv.y; bix = j * 64 + g * 4 + 1; }
  if (rv.z > bv) { bv = rv.z; bix = j * 64 + g * 4 + 2; }
  if (rv.w > bv) { bv = rv.w; bix = j * 64 + g * 4 + 3; }
  int cnt = (rv.x > thr ? 1 : 0) + (rv.y > thr ? 1 : 0) +
            (rv.z > thr ? 1 : 0) + (rv.w > thr ? 1 : 0);
#pragma unroll
  for (int off = 1; off < 16; off <<= 1) {
    const float ov = __shfl_xor(bv, off, 64);
    const int oi = __shfl_xor(bix, off, 64);
    cnt += __shfl_xor(cnt, off, 64);
    if (ov > bv || (ov == bv && oi < bix)) { bv = ov; bix = oi; }
  }

  const bool fast = (nflag == 1) && (cnt == 1);
  float lval = 0.0f;
  if (fast && g == 0) {
    out[IDX_OFF + n] = (float)bix;
    lval = bv * bv;
  }

  // slow tokens: whole wave runs the round-1 full-row algorithm per token
  unsigned long long smask = __ballot((!fast) && (g == 0));
  float sloss = 0.0f;
  while (smask) {
    const int sl = __ffsll((long long)smask) - 1;
    smask &= smask - 1;
    const int nn = blockIdx.x * 16 + w * 4 + (sl >> 4);
    {
      const float* row = out + DIST_OFF + (size_t)nn * C_NUM;
      float v[16];
      float bestf = -3.4e38f;
      int bif = 0x7fffffff;
#pragma unroll
      for (int jj = 0; jj < 16; ++jj) {
        v[jj] = row[jj * 64 + lane];
        if (v[jj] > bestf) { bestf = v[jj]; bif = jj * 64 + lane; }
      }
#pragma unroll
      for (int off = 32; off; off >>= 1) {
        const float ov = __shfl_xor(bestf, off, 64);
        const int oi = __shfl_xor(bif, off, 64);
        if (ov > bestf || (ov == bestf && oi < bif)) { bestf = ov; bif = oi; }
      }
      const float thrf = bestf - MARGIN;
      unsigned long long masks[16];
      int total = 0;
#pragma unroll
      for (int jj = 0; jj < 16; ++jj) {
        masks[jj] = __ballot(v[jj] > thrf);
        total += __popcll(masks[jj]);
      }
      float best_d2 = bestf * bestf;
      int best_idx = bif;
      if (total > 1) {
        best_d2 = 3.4e38f;
        best_idx = 0x7fffffff;
        for (int jj = 0; jj < 16; ++jj) {
          unsigned long long mm = masks[jj];
          while (mm) {
            const int l = __ffsll((long long)mm) - 1;
            mm &= mm - 1;
            const int c = jj * 64 + l;
            float sx = 0.f, se = 0.f, sxe = 0.f;
#pragma unroll
            for (int r = 0; r < 4; ++r) {
              const int d = r * 64 + lane;
              const float xv = X[(size_t)d * N_TOK + nn];
              const float ev = E[(size_t)c * D_DIM + d];
              sx = fmaf(xv, xv, sx);
              se = fmaf(ev, ev, se);
              sxe = fmaf(xv, ev, sxe);
            }
            float d2 = fmaf(-2.f, sxe, sx + se);
#pragma unroll
            for (int off = 32; off; off >>= 1) d2 += __shfl_xor(d2, off, 64);
            d2 = fmaxf(d2, 0.f);
            if (d2 < best_d2 || (d2 == best_d2 && c < best_idx)) {
              best_d2 = d2; best_idx = c;
            }
          }
        }
      }
      if (lane == 0) {
        out[IDX_OFF + nn] = (float)best_idx;
        sloss += best_d2;
      }
    }
  }

  float wl = lval + ((lane == 0) ? sloss : 0.0f);
#pragma unroll
  for (int off = 32; off; off >>= 1) wl += __shfl_down(wl, off, 64);
  if (lane == 0) lsum[w] = wl;
  __syncthreads();
  if (tid == 0)
    part[blockIdx.x] = lsum[0] + lsum[1] + lsum[2] + lsum[3];
}

__global__ __launch_bounds__(256) void k3b2_loss(float* __restrict__ out,
                                                 unsigned char* __restrict__ ws) {
  const float* __restrict__ part = (const float*)(ws + WS_PART);
  __shared__ float red[4];
  const int tid = threadIdx.x, lane = tid & 63, w = tid >> 6;
  float s = 0.0f;
#pragma unroll
  for (int i = 0; i < NPART / 256; ++i) s += part[i * 256 + tid];
#pragma unroll
  for (int off = 32; off; off >>= 1) s += __shfl_down(s, off, 64);
  if (lane == 0) red[w] = s;
  __syncthreads();
  if (tid == 0)
    out[LOSS_OFF] = (red[0] + red[1] + red[2] + red[3]) *
                    (0.25f / ((float)N_TOK * (float)D_DIM));
}

// ===========================================================================
// PATH B (fallback, ws unusable): round-1 kernels verbatim.
// ===========================================================================
#define EH_OFF_F  0
#define EL_OFF_F  131072
#define E2_OFF_F  262144

__global__ __launch_bounds__(256) void kA_prep(const float* __restrict__ X,
                                               const float* __restrict__ E,
                                               float* __restrict__ out) {
  const int bid = blockIdx.x, tid = threadIdx.x;
  if (bid < 256) {
    const int n = bid * 256 + tid;
    float s = 0.0f;
#pragma unroll 8
    for (int d = 0; d < D_DIM; ++d) {
      float v = X[(size_t)d * N_TOK + n];
      s = fmaf(v, v, s);
    }
    out[IDX_OFF + n] = s;
  } else {
    unsigned short* EhG = (unsigned short*)(out + EH_OFF_F);
    unsigned short* ElG = (unsigned short*)(out + EL_OFF_F);
    const int lane = tid & 63, w = tid >> 6;
#pragma unroll 1
    for (int cc = 0; cc < 16; ++cc) {
      const int c = (bid - 256) * 64 + w * 16 + cc;
      const float4 v = *(const float4*)(E + (size_t)c * D_DIM + lane * 4);
      unsigned short h0 = f2bf(v.x), h1 = f2bf(v.y), h2 = f2bf(v.z), h3 = f2bf(v.w);
      unsigned short l0 = f2bf(v.x - bf2f(h0)), l1 = f2bf(v.y - bf2f(h1));
      unsigned short l2 = f2bf(v.z - bf2f(h2)), l3 = f2bf(v.w - bf2f(h3));
      ushort4 hv = make_ushort4(h0, h1, h2, h3);
      ushort4 lv = make_ushort4(l0, l1, l2, l3);
      *(ushort4*)(EhG + (size_t)c * D_DIM + lane * 4) = hv;
      *(ushort4*)(ElG + (size_t)c * D_DIM + lane * 4) = lv;
      float s = v.x * v.x + v.y * v.y + v.z * v.z + v.w * v.w;
#pragma unroll
      for (int off = 32; off; off >>= 1) s += __shfl_down(s, off, 64);
      if (lane == 0) out[E2_OFF_F + c] = s;
    }
  }
}

#define XS 40

__global__ __launch_bounds__(256) void k2_dist(const float* __restrict__ X,
                                               float* __restrict__ out) {
  __shared__ __align__(16) unsigned short xhb[2][TM * XS];
  __shared__ __align__(16) unsigned short xlb[2][TM * XS];

  const unsigned short* __restrict__ EhG = (const unsigned short*)(out + EH_OFF_F);
  const unsigned short* __restrict__ ElG = (const unsigned short*)(out + EL_OFF_F);

  const int tid = threadIdx.x;
  const int lane = tid & 63, wave = tid >> 6;
  const int bid = blockIdx.x;
  const int xcd = bid & 7;
  const int slot = bid >> 3;
  const int bx = slot & 3;
  const int by = xcd * 128 + (slot >> 2);
  const int c0 = bx * TC;
  const int n0 = by * TM;

  const int wc = c0 + wave * 64;
  const int m = lane & 15;
  const int q = lane >> 4;

  f32x4 acc[4][4];
#pragma unroll
  for (int i = 0; i < 4; ++i)
#pragma unroll
    for (int t = 0; t < 4; ++t) acc[i][t] = (f32x4){0.f, 0.f, 0.f, 0.f};

  const int sn = lane;
  const int kg = wave;

  float xv[8];
  {
    const float* xp = X + (size_t)(kg * 8) * N_TOK + n0 + sn;
#pragma unroll
    for (int j = 0; j < 8; ++j) xv[j] = xp[(size_t)j * N_TOK];
  }

#pragma unroll 1
  for (int kb = 0; kb < D_DIM; kb += BK) {
    const int p = (kb >> 5) & 1;
    bf16x8 bh[4], bl[4];
#pragma unroll
    for (int t = 0; t < 4; ++t) {
      const size_t eoff = (size_t)(wc + t * 16 + m) * D_DIM + kb + q * 8;
      bh[t] = *(const bf16x8*)(EhG + eoff);
      bl[t] = *(const bf16x8*)(ElG + eoff);
    }
    unsigned short hh[8], ll[8];
#pragma unroll
    for (int j = 0; j < 8; ++j) {
      hh[j] = f2bf(xv[j]);
      ll[j] = f2bf(xv[j] - bf2f(hh[j]));
    }
    *(bf16x8*)&xhb[p][sn * XS + kg * 8] = *(bf16x8*)hh;
    *(bf16x8*)&xlb[p][sn * XS + kg * 8] = *(bf16x8*)ll;
    if (kb + BK < D_DIM) {
      const float* xp = X + (size_t)(kb + BK + kg * 8) * N_TOK + n0 + sn;
#pragma unroll
      for (int j = 0; j < 8; ++j) xv[j] = xp[(size_t)j * N_TOK];
    }
    __syncthreads();
    bf16x8 ah[4], al[4];
#pragma unroll
    for (int i = 0; i < 4; ++i) {
      const int ro = (i * 16 + m) * XS + q * 8;
      ah[i] = *(const bf16x8*)&xhb[p][ro];
      al[i] = *(const bf16x8*)&xlb[p][ro];
    }
#pragma unroll
    for (int i = 0; i < 4; ++i)
#pragma unroll
      for (int t = 0; t < 4; ++t) {
        acc[i][t] = __builtin_amdgcn_mfma_f32_16x16x32_bf16(ah[i], bh[t], acc[i][t], 0, 0, 0);
        acc[i][t] = __builtin_amdgcn_mfma_f32_16x16x32_bf16(ah[i], bl[t], acc[i][t], 0, 0, 0);
        acc[i][t] = __builtin_amdgcn_mfma_f32_16x16x32_bf16(al[i], bh[t], acc[i][t], 0, 0, 0);
      }
  }

  float e2v[4];
#pragma unroll
  for (int t = 0; t < 4; ++t) e2v[t] = out[E2_OFF_F + wc + t * 16 + m];

#pragma unroll
  for (int i = 0; i < 4; ++i) {
#pragma unroll
    for (int r = 0; r < 4; ++r) {
      const int tok = n0 + i * 16 + q * 4 + r;
      const float x2v = out[IDX_OFF + tok];
      const size_t row = DIST_OFF + (size_t)tok * C_NUM;
#pragma unroll
      for (int t = 0; t < 4; ++t) {
        float d2 = fmaf(-2.0f, acc[i][t][r], x2v + e2v[t]);
        d2 = fmaxf(d2, 0.0f);
        out[row + wc + t * 16 + m] = -sqrtf(d2);
      }
    }
  }
}

__global__ __launch_bounds__(256) void k3_argmax(const float* __restrict__ X,
                                                 const float* __restrict__ E,
                                                 float* __restrict__ out) {
  __shared__ float lsum[4];
  const int tid = threadIdx.x, lane = tid & 63, w = tid >> 6;
  float wloss = 0.0f;

#pragma unroll 1
  for (int it = 0; it < 4; ++it) {
    const int n = blockIdx.x * 16 + w * 4 + it;
    const float* row = out + DIST_OFF + (size_t)n * C_NUM;

    float v[16];
    float best = -3.4e38f;
    int bi = 0x7fffffff;
#pragma unroll
    for (int j = 0; j < 16; ++j) {
      v[j] = row[j * 64 + lane];
      if (v[j] > best) { best = v[j]; bi = j * 64 + lane; }
    }
#pragma unroll
    for (int off = 32; off; off >>= 1) {
      const float ov = __shfl_xor(best, off, 64);
      const int oi = __shfl_xor(bi, off, 64);
      if (ov > best || (ov == best && oi < bi)) { best = ov; bi = oi; }
    }
    const float thr = best - MARGIN;
    unsigned long long masks[16];
    int total = 0;
#pragma unroll
    for (int j = 0; j < 16; ++j) {
      masks[j] = __ballot(v[j] > thr);
      total += __popcll(masks[j]);
    }
    float best_d2 = best * best;
    int best_idx = bi;
    if (total > 1) {
      best_d2 = 3.4e38f;
      best_idx = 0x7fffffff;
      for (int j = 0; j < 16; ++j) {
        unsigned long long mm = masks[j];
        while (mm) {
          const int l = __ffsll((long long)mm) - 1;
          mm &= mm - 1;
          const int c = j * 64 + l;
          float sx = 0.f, se = 0.f, sxe = 0.f;
#pragma unroll
          for (int r = 0; r < 4; ++r) {
            const int d = r * 64 + lane;
            const float xv = X[(size_t)d * N_TOK + n];
            const float ev = E[(size_t)c * D_DIM + d];
            sx = fmaf(xv, xv, sx);
            se = fmaf(ev, ev, se);
            sxe = fmaf(xv, ev, sxe);
          }
          float d2 = fmaf(-2.f, sxe, sx + se);
#pragma unroll
          for (int off = 32; off; off >>= 1) d2 += __shfl_xor(d2, off, 64);
          d2 = fmaxf(d2, 0.f);
          if (d2 < best_d2 || (d2 == best_d2 && c < best_idx)) {
            best_d2 = d2; best_idx = c;
          }
        }
      }
    }
    if (lane == 0) out[IDX_OFF + n] = (float)best_idx;
    wloss += best_d2;
  }
  if (lane == 0) lsum[w] = wloss;
  __syncthreads();
  if (tid == 0)
    out[PART_OFF_F + blockIdx.x] = lsum[0] + lsum[1] + lsum[2] + lsum[3];
}

__global__ __launch_bounds__(256) void k3b_loss(float* __restrict__ out) {
  __shared__ float red[4];
  const int tid = threadIdx.x, lane = tid & 63, w = tid >> 6;
  float s = 0.0f;
#pragma unroll
  for (int i = 0; i < NPART / 256; ++i) s += out[PART_OFF_F + i * 256 + tid];
#pragma unroll
  for (int off = 32; off; off >>= 1) s += __shfl_down(s, off, 64);
  if (lane == 0) red[w] = s;
  __syncthreads();
  if (tid == 0)
    out[LOSS_OFF] = (red[0] + red[1] + red[2] + red[3]) *
                    (0.25f / ((float)N_TOK * (float)D_DIM));
}

// ---------------------------------------------------------------------------
// k4: shared by both paths. out[d][n] = E[idx[n]][d]. float4 index load.
// ---------------------------------------------------------------------------
__global__ __launch_bounds__(256) void k4_gather(const float* __restrict__ E,
                                                 float* __restrict__ out) {
  const int g = blockIdx.x * 256 + threadIdx.x;
  const int n = g * 4;
  const float4 iv = *(const float4*)&out[IDX_OFF + n];
  const int i0 = (int)iv.x;
  const int i1 = (int)iv.y;
  const int i2 = (int)iv.z;
  const int i3 = (int)iv.w;
  const float* e0 = E + (size_t)i0 * D_DIM;
  const float* e1 = E + (size_t)i1 * D_DIM;
  const float* e2 = E + (size_t)i2 * D_DIM;
  const float* e3 = E + (size_t)i3 * D_DIM;
  const int d0 = blockIdx.y * 32;
#pragma unroll 4
  for (int d = d0; d < d0 + 32; ++d) {
    float4 wv = make_float4(e0[d], e1[d], e2[d], e3[d]);
    *(float4*)&out[(size_t)d * N_TOK + n] = wv;
  }
}

extern "C" void kernel_launch(void* const* d_in, const int* in_sizes, int n_in,
                              void* d_out, int out_size, void* d_ws, size_t ws_size,
                              hipStream_t stream) {
  const float* X = (const float*)d_in[0];   // (1, 256, 65536)
  const float* E = (const float*)d_in[1];   // (1, 1024, 256)
  float* out = (float*)d_out;

  if (ws_size >= WS_NEEDED && d_ws != nullptr) {
    unsigned char* ws = (unsigned char*)d_ws;
    hipLaunchKernelGGL(kA2_prep, dim3(1040), dim3(256), 0, stream, X, E, out, ws);
    hipLaunchKernelGGL(k2c_dist, dim3((C_NUM / TC) * (N_TOK / TM)), dim3(256), 0,
                       stream, out, ws);
    hipLaunchKernelGGL(k3a4_argmax, dim3(N_TOK / 16), dim3(256), 0, stream,
                       X, E, out, ws);
    hipLaunchKernelGGL(k3b2_loss, dim3(1), dim3(256), 0, stream, out, ws);
    hipLaunchKernelGGL(k4_gather, dim3(N_TOK / 4 / 256, 8), dim3(256), 0, stream,
                       E, out);
  } else {
    hipLaunchKernelGGL(kA_prep, dim3(272), dim3(256), 0, stream, X, E, out);
    hipLaunchKernelGGL(k2_dist, dim3((C_NUM / TC) * (N_TOK / TM)), dim3(256), 0,
                       stream, X, out);
    hipLaunchKernelGGL(k3_argmax, dim3(N_TOK / 16), dim3(256), 0, stream, X, E, out);
    hipLaunchKernelGGL(k3b_loss, dim3(1), dim3(256), 0, stream, out);
    hipLaunchKernelGGL(k4_gather, dim3(N_TOK / 4 / 256, 8), dim3(256), 0, stream,
                       E, out);
  }
}

// Round 9
// 590.668 us; speedup vs baseline: 1.1868x; 1.0402x over previous
//
#include <hip/hip_runtime.h>
#include <math.h>

#define N_TOK 65536
#define D_DIM 256
#define C_NUM 1024

// d_out layout (floats): out (D*N) | indices (N) | loss (1) | distances (N*C)
#define OUT_OFF   0
#define IDX_OFF   (D_DIM * N_TOK)            // 16777216
#define LOSS_OFF  (IDX_OFF + N_TOK)          // 16842752
#define DIST_OFF  (LOSS_OFF + 1)             // 16842753

#define MARGIN 0.01f
#define NPART 4096

typedef __attribute__((ext_vector_type(8))) short bf16x8;
typedef __attribute__((ext_vector_type(4))) float f32x4;

static __device__ __forceinline__ unsigned short f2bf(float f) {
  unsigned int u = __float_as_uint(f);
  unsigned int r = (u + 0x7fffu + ((u >> 16) & 1u)) >> 16;
  return (unsigned short)r;
}
static __device__ __forceinline__ float bf2f(unsigned short h) {
  return __uint_as_float(((unsigned int)h) << 16);
}

// ===========================================================================
// PATH A (ws_size >= WS_NEEDED):
//   out region (64MB, dead until k4) holds Xh (32MB) | Xl (32MB), [n][k] bf16.
//   x2 lives in IDX region (overwritten by k3a4's indices later).
//   ws: Eh | El | e2 | loss partials | per-(token,group) best-VALUE records.
// Round-9 deltas vs round-8 (independent, per-kernel attributable):
//   kA2: coalesced-read LDS-transpose X pass (warp reads 256B rows, 64x64
//        u16 tile stride-72, b128 LDS writes/reads, b128 global writes).
//        Same f2bf bytes; x2 accumulation order differs (validated class:
//        uniform per-token shift, argmax invariant).
//   k2c: #pragma unroll 4 on K-loop + s_setprio(1/0) around MFMA cluster
//        (waves free-run after the single barrier -> setprio regime).
//   k4:  E-row gathers as float4 + 4x4 in-register transpose (same values).
// ===========================================================================

// ws byte offsets
#define WS_EH   0                            // u16[1024*256]   512KB
#define WS_EL   524288                       // u16[1024*256]   512KB
#define WS_E2   1048576                      // f32[1024]       4KB
#define WS_PART 1052672                      // f32[4096]       16KB
#define WS_TP   1069056                      // f32[65536*16]   4MB
#define WS_NEEDED (WS_TP + (size_t)N_TOK * 16 * 4)

// Xh/Xl float offsets inside out region
#define XH_OFF_F 0
#define XL_OFF_F 8388608

// loss partials float offset (path B only; inside dead region)
#define PART_OFF_F 263168

// ---------------------------------------------------------------------------
// kA2: bid<1024: coalesced transpose+convert X -> Xh/Xl [n][k] + x2.
//      1024..1039: convert E -> Eh/El + e2 (in ws). (E part verbatim.)
// X part per 64-d chunk: warp w reads rows dc+w*16+j (256B coalesced),
// packs bf16 hi/lo into LDS [64 tok][72 u16] via b128, then threads write
// [token][d] b128 rows to global. x2: per-warp partials -> LDS reduce.
// ---------------------------------------------------------------------------
#define TS 72   // u16 stride for the 64x64 transpose tile (16B-aligned rows)

__global__ __launch_bounds__(256) void kA2_prep(const float* __restrict__ X,
                                                const float* __restrict__ E,
                                                float* __restrict__ out,
                                                unsigned char* __restrict__ ws) {
  const int bid = blockIdx.x, tid = threadIdx.x;
  if (bid < 1024) {
    __shared__ __align__(16) unsigned short lh[64 * TS];
    __shared__ __align__(16) unsigned short ll[64 * TS];
    __shared__ float xs2[4][64];

    unsigned short* XhG = (unsigned short*)(out + XH_OFF_F);
    unsigned short* XlG = (unsigned short*)(out + XL_OFF_F);
    const int lane = tid & 63, w = tid >> 6;
    const int n0 = bid * 64;
    const int tl = tid >> 2;                 // write-phase token
    const int sg = (tid & 3) * 16;           // write-phase d-segment

    float s = 0.0f;
#pragma unroll 1
    for (int dc = 0; dc < D_DIM; dc += 64) {
      // ---- read 16 rows, coalesced 256B per row per warp ----
      float v[16];
#pragma unroll
      for (int j = 0; j < 16; ++j)
        v[j] = X[(size_t)(dc + w * 16 + j) * N_TOK + n0 + lane];
      unsigned short hh[16], llv[16];
#pragma unroll
      for (int j = 0; j < 16; ++j) {
        s = fmaf(v[j], v[j], s);
        hh[j] = f2bf(v[j]);
        llv[j] = f2bf(v[j] - bf2f(hh[j]));
      }
      // lane's 16 consecutive columns -> two b128 LDS writes each
      *(bf16x8*)&lh[lane * TS + w * 16] = *(bf16x8*)&hh[0];
      *(bf16x8*)&lh[lane * TS + w * 16 + 8] = *(bf16x8*)&hh[8];
      *(bf16x8*)&ll[lane * TS + w * 16] = *(bf16x8*)&llv[0];
      *(bf16x8*)&ll[lane * TS + w * 16 + 8] = *(bf16x8*)&llv[8];
      __syncthreads();
      // ---- write phase: [token][d] b128 rows to global ----
      {
        const bf16x8 h0 = *(const bf16x8*)&lh[tl * TS + sg];
        const bf16x8 h1 = *(const bf16x8*)&lh[tl * TS + sg + 8];
        const bf16x8 l0 = *(const bf16x8*)&ll[tl * TS + sg];
        const bf16x8 l1 = *(const bf16x8*)&ll[tl * TS + sg + 8];
        unsigned short* gh = XhG + (size_t)(n0 + tl) * D_DIM + dc + sg;
        unsigned short* gl = XlG + (size_t)(n0 + tl) * D_DIM + dc + sg;
        *(bf16x8*)gh = h0;
        *(bf16x8*)(gh + 8) = h1;
        *(bf16x8*)gl = l0;
        *(bf16x8*)(gl + 8) = l1;
      }
      __syncthreads();
    }
    // ---- x2: per-warp partials (rows w*16+j over all chunks) -> reduce ----
    xs2[w][lane] = s;
    __syncthreads();
    if (w == 0) {
      const float t2 = (xs2[0][lane] + xs2[1][lane]) +
                       (xs2[2][lane] + xs2[3][lane]);
      out[IDX_OFF + n0 + lane] = t2;
    }
  } else {
    unsigned short* EhG = (unsigned short*)(ws + WS_EH);
    unsigned short* ElG = (unsigned short*)(ws + WS_EL);
    float* e2p = (float*)(ws + WS_E2);
    const int lane = tid & 63, w = tid >> 6;
#pragma unroll 1
    for (int cc = 0; cc < 16; ++cc) {
      const int c = (bid - 1024) * 64 + w * 16 + cc;
      const float4 v = *(const float4*)(E + (size_t)c * D_DIM + lane * 4);
      unsigned short h0 = f2bf(v.x), h1 = f2bf(v.y), h2 = f2bf(v.z), h3 = f2bf(v.w);
      unsigned short l0 = f2bf(v.x - bf2f(h0)), l1 = f2bf(v.y - bf2f(h1));
      unsigned short l2 = f2bf(v.z - bf2f(h2)), l3 = f2bf(v.w - bf2f(h3));
      ushort4 hv = make_ushort4(h0, h1, h2, h3);
      ushort4 lv = make_ushort4(l0, l1, l2, l3);
      *(ushort4*)(EhG + (size_t)c * D_DIM + lane * 4) = hv;
      *(ushort4*)(ElG + (size_t)c * D_DIM + lane * 4) = lv;
      float s = v.x * v.x + v.y * v.y + v.z * v.z + v.w * v.w;
#pragma unroll
      for (int off = 32; off; off >>= 1) s += __shfl_down(s, off, 64);
      if (lane == 0) e2p[c] = s;
    }
  }
}

// ---------------------------------------------------------------------------
// k2c: stage-once Xh+Xl LDS, one barrier, unroll-4 K-loop with setprio'd
// MFMA cluster, x2/e2 hoisted, value-only record epilogue.
// Block = 64 tokens x 256 codes, 4 waves; wave w owns 64 codes.
// ---------------------------------------------------------------------------
#define TM 64
#define TC 256
#define BK 32
#define XS2 264   // u16 row stride (256 + 8 pad); 528B, 16B-aligned

__global__ __launch_bounds__(256) void k2c_dist(float* __restrict__ out,
                                                unsigned char* __restrict__ ws) {
  __shared__ __align__(16) unsigned short xh[TM * XS2];
  __shared__ __align__(16) unsigned short xl[TM * XS2];

  const unsigned short* __restrict__ XhG = (const unsigned short*)(out + XH_OFF_F);
  const unsigned short* __restrict__ XlG = (const unsigned short*)(out + XL_OFF_F);
  const unsigned short* __restrict__ EhG = (const unsigned short*)(ws + WS_EH);
  const float* __restrict__ e2p = (const float*)(ws + WS_E2);
  float* __restrict__ tpv = (float*)(ws + WS_TP);

  const int tid = threadIdx.x;
  const int lane = tid & 63, wave = tid >> 6;

  // XCD-swizzled decode (4 code-tiles of a token-tile land on the same XCD)
  const int bid = blockIdx.x;
  const int xcd = bid & 7;
  const int slot = bid >> 3;
  const int bx = slot & 3;
  const int by = xcd * 128 + (slot >> 2);
  const int c0 = bx * TC;
  const int n0 = by * TM;

  const int wc = c0 + wave * 64;
  const int m = lane & 15;
  const int q = lane >> 4;

  // ---- stage whole A-tile once: thread owns token tl, 64-u16 segment ----
  {
    const int tl = tid >> 2;
    const int seg = (tid & 3) * 64;
    const unsigned short* gh = XhG + (size_t)(n0 + tl) * D_DIM + seg;
    const unsigned short* gl = XlG + (size_t)(n0 + tl) * D_DIM + seg;
    unsigned short* sh = xh + tl * XS2 + seg;
    unsigned short* sl = xl + tl * XS2 + seg;
#pragma unroll
    for (int j = 0; j < 8; ++j) {
      *(bf16x8*)(sh + j * 8) = *(const bf16x8*)(gh + j * 8);
      *(bf16x8*)(sl + j * 8) = *(const bf16x8*)(gl + j * 8);
    }
  }

  // ---- hoisted epilogue operands: issue loads before the long K-loop ----
  float x2r[16];
#pragma unroll
  for (int i = 0; i < 4; ++i)
#pragma unroll
    for (int r = 0; r < 4; ++r)
      x2r[i * 4 + r] = out[IDX_OFF + n0 + i * 16 + q * 4 + r];
  float e2v[4];
#pragma unroll
  for (int t = 0; t < 4; ++t) e2v[t] = e2p[wc + t * 16 + m];

  __syncthreads();   // the only barrier in this kernel

  f32x4 acc[4][4];
#pragma unroll
  for (int i = 0; i < 4; ++i)
#pragma unroll
    for (int t = 0; t < 4; ++t) acc[i][t] = (f32x4){0.f, 0.f, 0.f, 0.f};

  // hoisted B fragment base pointers (row*256 + q*8), offset by kb in loop
  const unsigned short* bp[4];
#pragma unroll
  for (int t = 0; t < 4; ++t) bp[t] = EhG + (size_t)(wc + t * 16 + m) * D_DIM + q * 8;
  const size_t loEu = (size_t)(WS_EL - WS_EH) / 2;        // u16 delta Eh->El

#pragma unroll 4
  for (int kb = 0; kb < D_DIM; kb += BK) {
    bf16x8 ah[4], al[4], bh[4], bl[4];
#pragma unroll
    for (int t = 0; t < 4; ++t) {
      bh[t] = *(const bf16x8*)(bp[t] + kb);
      bl[t] = *(const bf16x8*)(bp[t] + loEu + kb);
    }
#pragma unroll
    for (int i = 0; i < 4; ++i) {
      const int ro = (i * 16 + m) * XS2 + kb + q * 8;
      ah[i] = *(const bf16x8*)&xh[ro];
      al[i] = *(const bf16x8*)&xl[ro];
    }
    __builtin_amdgcn_s_setprio(1);
#pragma unroll
    for (int i = 0; i < 4; ++i)
#pragma unroll
      for (int t = 0; t < 4; ++t) {
        acc[i][t] = __builtin_amdgcn_mfma_f32_16x16x32_bf16(ah[i], bh[t], acc[i][t], 0, 0, 0);
        acc[i][t] = __builtin_amdgcn_mfma_f32_16x16x32_bf16(ah[i], bl[t], acc[i][t], 0, 0, 0);
        acc[i][t] = __builtin_amdgcn_mfma_f32_16x16x32_bf16(al[i], bh[t], acc[i][t], 0, 0, 0);
      }
    __builtin_amdgcn_s_setprio(0);
  }

  // ---- epilogue: distances + value-only group-best record ----
#pragma unroll
  for (int i = 0; i < 4; ++i) {
#pragma unroll
    for (int r = 0; r < 4; ++r) {
      const int tok = n0 + i * 16 + q * 4 + r;
      const float x2v = x2r[i * 4 + r];
      const size_t row = DIST_OFF + (size_t)tok * C_NUM;
      float bestv = -3.4e38f;
#pragma unroll
      for (int t = 0; t < 4; ++t) {
        float d2 = fmaf(-2.0f, acc[i][t][r], x2v + e2v[t]);
        d2 = fmaxf(d2, 0.0f);
        const float dd = -sqrtf(d2);
        out[row + wc + t * 16 + m] = dd;
        bestv = fmaxf(bestv, dd);
      }
      // group max across the 16 m-lanes (stays within the q-group: off<16)
#pragma unroll
      for (int off = 1; off < 16; off <<= 1)
        bestv = fmaxf(bestv, __shfl_xor(bestv, off, 64));
      if ((lane & 15) == 0)
        tpv[(size_t)tok * 16 + bx * 4 + wave] = bestv;
    }
  }
}

// ---------------------------------------------------------------------------
// k3a4: 4 tokens per wave CONCURRENTLY (16 lanes each). Value-only records;
// fast path nflag==1 && cnt==1 == round-1's total==1 exactly; slow path is
// the round-1 full-row algorithm verbatim. (Validated round 8.)
// ---------------------------------------------------------------------------
__global__ __launch_bounds__(256) void k3a4_argmax(const float* __restrict__ X,
                                                   const float* __restrict__ E,
                                                   float* __restrict__ out,
                                                   unsigned char* __restrict__ ws) {
  const float* __restrict__ tpv = (const float*)(ws + WS_TP);
  float* __restrict__ part = (float*)(ws + WS_PART);
  __shared__ float lsum[4];
  const int tid = threadIdx.x, lane = tid & 63, w = tid >> 6;
  const int g = lane & 15, seg = lane >> 4;
  const int n = blockIdx.x * 16 + w * 4 + seg;

  const float gval = tpv[(size_t)n * 16 + g];
  float best = gval;
#pragma unroll
  for (int off = 1; off < 16; off <<= 1)
    best = fmaxf(best, __shfl_xor(best, off, 64));
  const float thr = best - MARGIN;
  const unsigned long long bal = __ballot(gval > thr);
  const unsigned m16 = (unsigned)((bal >> (seg * 16)) & 0xffffull);
  const int nflag = __popc(m16);
  const int j = __ffs(m16) - 1;            // first flagged group (nflag >= 1)

  // read the flagged group's 64-distance slice: 16 lanes x float4 = 256B
  const float4 rv =
      *(const float4*)(out + DIST_OFF + (size_t)n * C_NUM + j * 64 + g * 4);

  // lex-argmax (max val, min idx) + candidate count within the group
  float bv = rv.x;
  int bix = j * 64 + g * 4;
  if (rv.y > bv) { bv = rv.y; bix = j * 64 + g * 4 + 1; }
  if (rv.z > bv) { bv = rv.z; bix = j * 64 + g * 4 + 2; }
  if (rv.w > bv) { bv = rv.w; bix = j * 64 + g * 4 + 3; }
  int cnt = (rv.x > thr ? 1 : 0) + (rv.y > thr ? 1 : 0) +
            (rv.z > thr ? 1 : 0) + (rv.w > thr ? 1 : 0);
#pragma unroll
  for (int off = 1; off < 16; off <<= 1) {
    const float ov = __shfl_xor(bv, off, 64);
    const int oi = __shfl_xor(bix, off, 64);
    cnt += __shfl_xor(cnt, off, 64);
    if (ov > bv || (ov == bv && oi < bix)) { bv = ov; bix = oi; }
  }

  const bool fast = (nflag == 1) && (cnt == 1);
  float lval = 0.0f;
  if (fast && g == 0) {
    out[IDX_OFF + n] = (float)bix;
    lval = bv * bv;
  }

  // slow tokens: whole wave runs the round-1 full-row algorithm per token
  unsigned long long smask = __ballot((!fast) && (g == 0));
  float sloss = 0.0f;
  while (smask) {
    const int sl = __ffsll((long long)smask) - 1;
    smask &= smask - 1;
    const int nn = blockIdx.x * 16 + w * 4 + (sl >> 4);
    {
      const float* row = out + DIST_OFF + (size_t)nn * C_NUM;
      float v[16];
      float bestf = -3.4e38f;
      int bif = 0x7fffffff;
#pragma unroll
      for (int jj = 0; jj < 16; ++jj) {
        v[jj] = row[jj * 64 + lane];
        if (v[jj] > bestf) { bestf = v[jj]; bif = jj * 64 + lane; }
      }
#pragma unroll
      for (int off = 32; off; off >>= 1) {
        const float ov = __shfl_xor(bestf, off, 64);
        const int oi = __shfl_xor(bif, off, 64);
        if (ov > bestf || (ov == bestf && oi < bif)) { bestf = ov; bif = oi; }
      }
      const float thrf = bestf - MARGIN;
      unsigned long long masks[16];
      int total = 0;
#pragma unroll
      for (int jj = 0; jj < 16; ++jj) {
        masks[jj] = __ballot(v[jj] > thrf);
        total += __popcll(masks[jj]);
      }
      float best_d2 = bestf * bestf;
      int best_idx = bif;
      if (total > 1) {
        best_d2 = 3.4e38f;
        best_idx = 0x7fffffff;
        for (int jj = 0; jj < 16; ++jj) {
          unsigned long long mm = masks[jj];
          while (mm) {
            const int l = __ffsll((long long)mm) - 1;
            mm &= mm - 1;
            const int c = jj * 64 + l;
            float sx = 0.f, se = 0.f, sxe = 0.f;
#pragma unroll
            for (int r = 0; r < 4; ++r) {
              const int d = r * 64 + lane;
              const float xv = X[(size_t)d * N_TOK + nn];
              const float ev = E[(size_t)c * D_DIM + d];
              sx = fmaf(xv, xv, sx);
              se = fmaf(ev, ev, se);
              sxe = fmaf(xv, ev, sxe);
            }
            float d2 = fmaf(-2.f, sxe, sx + se);
#pragma unroll
            for (int off = 32; off; off >>= 1) d2 += __shfl_xor(d2, off, 64);
            d2 = fmaxf(d2, 0.f);
            if (d2 < best_d2 || (d2 == best_d2 && c < best_idx)) {
              best_d2 = d2; best_idx = c;
            }
          }
        }
      }
      if (lane == 0) {
        out[IDX_OFF + nn] = (float)best_idx;
        sloss += best_d2;
      }
    }
  }

  float wl = lval + ((lane == 0) ? sloss : 0.0f);
#pragma unroll
  for (int off = 32; off; off >>= 1) wl += __shfl_down(wl, off, 64);
  if (lane == 0) lsum[w] = wl;
  __syncthreads();
  if (tid == 0)
    part[blockIdx.x] = lsum[0] + lsum[1] + lsum[2] + lsum[3];
}

__global__ __launch_bounds__(256) void k3b2_loss(float* __restrict__ out,
                                                 unsigned char* __restrict__ ws) {
  const float* __restrict__ part = (const float*)(ws + WS_PART);
  __shared__ float red[4];
  const int tid = threadIdx.x, lane = tid & 63, w = tid >> 6;
  float s = 0.0f;
#pragma unroll
  for (int i = 0; i < NPART / 256; ++i) s += part[i * 256 + tid];
#pragma unroll
  for (int off = 32; off; off >>= 1) s += __shfl_down(s, off, 64);
  if (lane == 0) red[w] = s;
  __syncthreads();
  if (tid == 0)
    out[LOSS_OFF] = (red[0] + red[1] + red[2] + red[3]) *
                    (0.25f / ((float)N_TOK * (float)D_DIM));
}

// ===========================================================================
// PATH B (fallback, ws unusable): round-1 kernels verbatim.
// ===========================================================================
#define EH_OFF_F  0
#define EL_OFF_F  131072
#define E2_OFF_F  262144

__global__ __launch_bounds__(256) void kA_prep(const float* __restrict__ X,
                                               const float* __restrict__ E,
                                               float* __restrict__ out) {
  const int bid = blockIdx.x, tid = threadIdx.x;
  if (bid < 256) {
    const int n = bid * 256 + tid;
    float s = 0.0f;
#pragma unroll 8
    for (int d = 0; d < D_DIM; ++d) {
      float v = X[(size_t)d * N_TOK + n];
      s = fmaf(v, v, s);
    }
    out[IDX_OFF + n] = s;
  } else {
    unsigned short* EhG = (unsigned short*)(out + EH_OFF_F);
    unsigned short* ElG = (unsigned short*)(out + EL_OFF_F);
    const int lane = tid & 63, w = tid >> 6;
#pragma unroll 1
    for (int cc = 0; cc < 16; ++cc) {
      const int c = (bid - 256) * 64 + w * 16 + cc;
      const float4 v = *(const float4*)(E + (size_t)c * D_DIM + lane * 4);
      unsigned short h0 = f2bf(v.x), h1 = f2bf(v.y), h2 = f2bf(v.z), h3 = f2bf(v.w);
      unsigned short l0 = f2bf(v.x - bf2f(h0)), l1 = f2bf(v.y - bf2f(h1));
      unsigned short l2 = f2bf(v.z - bf2f(h2)), l3 = f2bf(v.w - bf2f(h3));
      ushort4 hv = make_ushort4(h0, h1, h2, h3);
      ushort4 lv = make_ushort4(l0, l1, l2, l3);
      *(ushort4*)(EhG + (size_t)c * D_DIM + lane * 4) = hv;
      *(ushort4*)(ElG + (size_t)c * D_DIM + lane * 4) = lv;
      float s = v.x * v.x + v.y * v.y + v.z * v.z + v.w * v.w;
#pragma unroll
      for (int off = 32; off; off >>= 1) s += __shfl_down(s, off, 64);
      if (lane == 0) out[E2_OFF_F + c] = s;
    }
  }
}

#define XS 40

__global__ __launch_bounds__(256) void k2_dist(const float* __restrict__ X,
                                               float* __restrict__ out) {
  __shared__ __align__(16) unsigned short xhb[2][TM * XS];
  __shared__ __align__(16) unsigned short xlb[2][TM * XS];

  const unsigned short* __restrict__ EhG = (const unsigned short*)(out + EH_OFF_F);
  const unsigned short* __restrict__ ElG = (const unsigned short*)(out + EL_OFF_F);

  const int tid = threadIdx.x;
  const int lane = tid & 63, wave = tid >> 6;
  const int bid = blockIdx.x;
  const int xcd = bid & 7;
  const int slot = bid >> 3;
  const int bx = slot & 3;
  const int by = xcd * 128 + (slot >> 2);
  const int c0 = bx * TC;
  const int n0 = by * TM;

  const int wc = c0 + wave * 64;
  const int m = lane & 15;
  const int q = lane >> 4;

  f32x4 acc[4][4];
#pragma unroll
  for (int i = 0; i < 4; ++i)
#pragma unroll
    for (int t = 0; t < 4; ++t) acc[i][t] = (f32x4){0.f, 0.f, 0.f, 0.f};

  const int sn = lane;
  const int kg = wave;

  float xv[8];
  {
    const float* xp = X + (size_t)(kg * 8) * N_TOK + n0 + sn;
#pragma unroll
    for (int j = 0; j < 8; ++j) xv[j] = xp[(size_t)j * N_TOK];
  }

#pragma unroll 1
  for (int kb = 0; kb < D_DIM; kb += BK) {
    const int p = (kb >> 5) & 1;
    bf16x8 bh[4], bl[4];
#pragma unroll
    for (int t = 0; t < 4; ++t) {
      const size_t eoff = (size_t)(wc + t * 16 + m) * D_DIM + kb + q * 8;
      bh[t] = *(const bf16x8*)(EhG + eoff);
      bl[t] = *(const bf16x8*)(ElG + eoff);
    }
    unsigned short hh[8], ll[8];
#pragma unroll
    for (int j = 0; j < 8; ++j) {
      hh[j] = f2bf(xv[j]);
      ll[j] = f2bf(xv[j] - bf2f(hh[j]));
    }
    *(bf16x8*)&xhb[p][sn * XS + kg * 8] = *(bf16x8*)hh;
    *(bf16x8*)&xlb[p][sn * XS + kg * 8] = *(bf16x8*)ll;
    if (kb + BK < D_DIM) {
      const float* xp = X + (size_t)(kb + BK + kg * 8) * N_TOK + n0 + sn;
#pragma unroll
      for (int j = 0; j < 8; ++j) xv[j] = xp[(size_t)j * N_TOK];
    }
    __syncthreads();
    bf16x8 ah[4], al[4];
#pragma unroll
    for (int i = 0; i < 4; ++i) {
      const int ro = (i * 16 + m) * XS + q * 8;
      ah[i] = *(const bf16x8*)&xhb[p][ro];
      al[i] = *(const bf16x8*)&xlb[p][ro];
    }
#pragma unroll
    for (int i = 0; i < 4; ++i)
#pragma unroll
      for (int t = 0; t < 4; ++t) {
        acc[i][t] = __builtin_amdgcn_mfma_f32_16x16x32_bf16(ah[i], bh[t], acc[i][t], 0, 0, 0);
        acc[i][t] = __builtin_amdgcn_mfma_f32_16x16x32_bf16(ah[i], bl[t], acc[i][t], 0, 0, 0);
        acc[i][t] = __builtin_amdgcn_mfma_f32_16x16x32_bf16(al[i], bh[t], acc[i][t], 0, 0, 0);
      }
  }

  float e2v[4];
#pragma unroll
  for (int t = 0; t < 4; ++t) e2v[t] = out[E2_OFF_F + wc + t * 16 + m];

#pragma unroll
  for (int i = 0; i < 4; ++i) {
#pragma unroll
    for (int r = 0; r < 4; ++r) {
      const int tok = n0 + i * 16 + q * 4 + r;
      const float x2v = out[IDX_OFF + tok];
      const size_t row = DIST_OFF + (size_t)tok * C_NUM;
#pragma unroll
      for (int t = 0; t < 4; ++t) {
        float d2 = fmaf(-2.0f, acc[i][t][r], x2v + e2v[t]);
        d2 = fmaxf(d2, 0.0f);
        out[row + wc + t * 16 + m] = -sqrtf(d2);
      }
    }
  }
}

__global__ __launch_bounds__(256) void k3_argmax(const float* __restrict__ X,
                                                 const float* __restrict__ E,
                                                 float* __restrict__ out) {
  __shared__ float lsum[4];
  const int tid = threadIdx.x, lane = tid & 63, w = tid >> 6;
  float wloss = 0.0f;

#pragma unroll 1
  for (int it = 0; it < 4; ++it) {
    const int n = blockIdx.x * 16 + w * 4 + it;
    const float* row = out + DIST_OFF + (size_t)n * C_NUM;

    float v[16];
    float best = -3.4e38f;
    int bi = 0x7fffffff;
#pragma unroll
    for (int j = 0; j < 16; ++j) {
      v[j] = row[j * 64 + lane];
      if (v[j] > best) { best = v[j]; bi = j * 64 + lane; }
    }
#pragma unroll
    for (int off = 32; off; off >>= 1) {
      const float ov = __shfl_xor(best, off, 64);
      const int oi = __shfl_xor(bi, off, 64);
      if (ov > best || (ov == best && oi < bi)) { best = ov; bi = oi; }
    }
    const float thr = best - MARGIN;
    unsigned long long masks[16];
    int total = 0;
#pragma unroll
    for (int j = 0; j < 16; ++j) {
      masks[j] = __ballot(v[j] > thr);
      total += __popcll(masks[j]);
    }
    float best_d2 = best * best;
    int best_idx = bi;
    if (total > 1) {
      best_d2 = 3.4e38f;
      best_idx = 0x7fffffff;
      for (int j = 0; j < 16; ++j) {
        unsigned long long mm = masks[j];
        while (mm) {
          const int l = __ffsll((long long)mm) - 1;
          mm &= mm - 1;
          const int c = j * 64 + l;
          float sx = 0.f, se = 0.f, sxe = 0.f;
#pragma unroll
          for (int r = 0; r < 4; ++r) {
            const int d = r * 64 + lane;
            const float xv = X[(size_t)d * N_TOK + n];
            const float ev = E[(size_t)c * D_DIM + d];
            sx = fmaf(xv, xv, sx);
            se = fmaf(ev, ev, se);
            sxe = fmaf(xv, ev, sxe);
          }
          float d2 = fmaf(-2.f, sxe, sx + se);
#pragma unroll
          for (int off = 32; off; off >>= 1) d2 += __shfl_xor(d2, off, 64);
          d2 = fmaxf(d2, 0.f);
          if (d2 < best_d2 || (d2 == best_d2 && c < best_idx)) {
            best_d2 = d2; best_idx = c;
          }
        }
      }
    }
    if (lane == 0) out[IDX_OFF + n] = (float)best_idx;
    wloss += best_d2;
  }
  if (lane == 0) lsum[w] = wloss;
  __syncthreads();
  if (tid == 0)
    out[PART_OFF_F + blockIdx.x] = lsum[0] + lsum[1] + lsum[2] + lsum[3];
}

__global__ __launch_bounds__(256) void k3b_loss(float* __restrict__ out) {
  __shared__ float red[4];
  const int tid = threadIdx.x, lane = tid & 63, w = tid >> 6;
  float s = 0.0f;
#pragma unroll
  for (int i = 0; i < NPART / 256; ++i) s += out[PART_OFF_F + i * 256 + tid];
#pragma unroll
  for (int off = 32; off; off >>= 1) s += __shfl_down(s, off, 64);
  if (lane == 0) red[w] = s;
  __syncthreads();
  if (tid == 0)
    out[LOSS_OFF] = (red[0] + red[1] + red[2] + red[3]) *
                    (0.25f / ((float)N_TOK * (float)D_DIM));
}

// ---------------------------------------------------------------------------
// k4: shared by both paths. out[d][n] = E[idx[n]][d]. float4 index load,
// float4 E-row gathers + 4x4 in-register transpose (same values/writes).
// ---------------------------------------------------------------------------
__global__ __launch_bounds__(256) void k4_gather(const float* __restrict__ E,
                                                 float* __restrict__ out) {
  const int g = blockIdx.x * 256 + threadIdx.x;
  const int n = g * 4;
  const float4 iv = *(const float4*)&out[IDX_OFF + n];
  const int i0 = (int)iv.x;
  const int i1 = (int)iv.y;
  const int i2 = (int)iv.z;
  const int i3 = (int)iv.w;
  const float* e0 = E + (size_t)i0 * D_DIM;
  const float* e1 = E + (size_t)i1 * D_DIM;
  const float* e2 = E + (size_t)i2 * D_DIM;
  const float* e3 = E + (size_t)i3 * D_DIM;
  const int d0 = blockIdx.y * 32;
#pragma unroll
  for (int dd = 0; dd < 32; dd += 4) {
    const float4 a0 = *(const float4*)&e0[d0 + dd];
    const float4 a1 = *(const float4*)&e1[d0 + dd];
    const float4 a2 = *(const float4*)&e2[d0 + dd];
    const float4 a3 = *(const float4*)&e3[d0 + dd];
    *(float4*)&out[(size_t)(d0 + dd + 0) * N_TOK + n] = make_float4(a0.x, a1.x, a2.x, a3.x);
    *(float4*)&out[(size_t)(d0 + dd + 1) * N_TOK + n] = make_float4(a0.y, a1.y, a2.y, a3.y);
    *(float4*)&out[(size_t)(d0 + dd + 2) * N_TOK + n] = make_float4(a0.z, a1.z, a2.z, a3.z);
    *(float4*)&out[(size_t)(d0 + dd + 3) * N_TOK + n] = make_float4(a0.w, a1.w, a2.w, a3.w);
  }
}

extern "C" void kernel_launch(void* const* d_in, const int* in_sizes, int n_in,
                              void* d_out, int out_size, void* d_ws, size_t ws_size,
                              hipStream_t stream) {
  const float* X = (const float*)d_in[0];   // (1, 256, 65536)
  const float* E = (const float*)d_in[1];   // (1, 1024, 256)
  float* out = (float*)d_out;

  if (ws_size >= WS_NEEDED && d_ws != nullptr) {
    unsigned char* ws = (unsigned char*)d_ws;
    hipLaunchKernelGGL(kA2_prep, dim3(1040), dim3(256), 0, stream, X, E, out, ws);
    hipLaunchKernelGGL(k2c_dist, dim3((C_NUM / TC) * (N_TOK / TM)), dim3(256), 0,
                       stream, out, ws);
    hipLaunchKernelGGL(k3a4_argmax, dim3(N_TOK / 16), dim3(256), 0, stream,
                       X, E, out, ws);
    hipLaunchKernelGGL(k3b2_loss, dim3(1), dim3(256), 0, stream, out, ws);
    hipLaunchKernelGGL(k4_gather, dim3(N_TOK / 4 / 256, 8), dim3(256), 0, stream,
                       E, out);
  } else {
    hipLaunchKernelGGL(kA_prep, dim3(272), dim3(256), 0, stream, X, E, out);
    hipLaunchKernelGGL(k2_dist, dim3((C_NUM / TC) * (N_TOK / TM)), dim3(256), 0,
                       stream, X, out);
    hipLaunchKernelGGL(k3_argmax, dim3(N_TOK / 16), dim3(256), 0, stream, X, E, out);
    hipLaunchKernelGGL(k3b_loss, dim3(1), dim3(256), 0, stream, out);
    hipLaunchKernelGGL(k4_gather, dim3(N_TOK / 4 / 256, 8), dim3(256), 0, stream,
                       E, out);
  }
}